// Round 18
// baseline (629.238 us; speedup 1.0000x reference)
//
#include <hip/hip_runtime.h>

// Social-LSTM trajectory model, v18.
// Encoder: v6 verbatim (persistent bf16-MFMA, 261 us).
// Decoder: re-tiled to 16 agents/block with mfma_f32_16x16x32_bf16 ->
// 256 blocks = ALL 256 CUs active (v14's 128-block grid idled half the chip).
// 8 stages/step of 8KB (async global_load_lds, counted vmcnt(8)).

#define S_TOT 86016   // 4096 hist + 81920 nbrs
#define NB    4096
#define NNB   81920
#define TT    16
#define NFUT  24
#define HXS   104     // encoder LDS row stride in bf16 (16B-aligned rows)
#define L2E   1.44269504088896f

typedef __attribute__((ext_vector_type(8)))  short short8v;
typedef __attribute__((ext_vector_type(16))) float f32x16;
typedef __attribute__((ext_vector_type(4)))  float f32x4v;

__device__ __forceinline__ float rcpf(float x) { return __builtin_amdgcn_rcpf(x); }
__device__ __forceinline__ float sigm2(float a)  { return rcpf(1.0f + exp2f(-a)); }
__device__ __forceinline__ float tanh2(float a)  { return 1.0f - 2.0f * rcpf(exp2f(a) + 1.0f); }
__device__ __forceinline__ float tanhx(float x)  { return tanh2(x * (2.0f * L2E)); }
__device__ __forceinline__ float lrelu(float v)  { return v >= 0.0f ? v : 0.1f * v; }
__device__ __forceinline__ short f2bf(float f) {            // RNE fp32->bf16
    unsigned u = __float_as_uint(f);
    unsigned r = (u + 0x7fffu + ((u >> 16) & 1u)) >> 16;
    return (short)r;
}

// async global -> LDS (16B per lane, lds dst wave-uniform base + lane*16)
__device__ __forceinline__ void gl2lds(const short* g, short* l) {
    __builtin_amdgcn_global_load_lds(
        (const __attribute__((address_space(1))) void*)(g),
        (__attribute__((address_space(3))) void*)(l), 16, 0, 0);
}

// ===========================================================================
// ENCODER (v6 verbatim, measured 261 us)
// ===========================================================================
__global__ __launch_bounds__(64) void k_pack_encB(
    const float* __restrict__ wih, const float* __restrict__ whh,
    const float* __restrict__ bih, const float* __restrict__ bhh,
    short* __restrict__ pB, float* __restrict__ pbias)
{
    const int fi = blockIdx.x;          // 0..47
    const int cc = fi % 6, gg = fi / 6;
    const int gate = gg & 3, H = gg >> 2;
    const int lane = threadIdx.x;       // 0..63
    const int row  = gate * 64 + H * 32 + (lane & 31);
    const float sc = (gate == 2) ? 2.0f * L2E : L2E;
    short8v v;
#pragma unroll
    for (int u = 0; u < 8; u++) {
        const int k = cc * 16 + (lane >> 5) * 8 + u;
        const float f = (k < 32) ? wih[row * 32 + k] : whh[row * 64 + (k - 32)];
        v[u] = f2bf(f * sc);
    }
    *(short8v*)&pB[((size_t)fi * 64 + lane) * 8] = v;
    if (cc == 0 && lane < 32)
        pbias[H * 128 + gate * 32 + lane] = (bih[row] + bhh[row]) * sc;
}

__global__ __launch_bounds__(256, 2) void k_encoder(
    const float* __restrict__ ctx_raw,  // (T, B, 2)
    const float* __restrict__ nbr_raw,  // (T, N, 2)
    const float* __restrict__ ipw, const float* __restrict__ ipb,
    const short* __restrict__ pB, const float* __restrict__ pbias,
    float* __restrict__ hfin)           // [S_TOT][64]
{
    __shared__ short hx2[2 * 64 * HXS];
    const int tid  = threadIdx.x;
    const int lane = tid & 63;
    const int w    = __builtin_amdgcn_readfirstlane(tid >> 6);  // 0..3
    const int H    = w >> 1;
    const int M0   = (w & 1) * 32;
    const int seq_base = blockIdx.x * 64;
    const bool is_hist = (seq_base < NB);

    short8v Bf[4][6];
#pragma unroll
    for (int gate = 0; gate < 4; gate++)
#pragma unroll
        for (int cc = 0; cc < 6; cc++)
            Bf[gate][cc] = *(const short8v*)
                &pB[(((size_t)(H * 4 + gate) * 6 + cc) * 64 + lane) * 8];

    float b4[4];
#pragma unroll
    for (int gate = 0; gate < 4; gate++)
        b4[gate] = pbias[H * 128 + gate * 32 + (lane & 31)];

    {
        short8v z;
#pragma unroll
        for (int u = 0; u < 8; u++) z[u] = 0;
        for (int i = tid; i < 64 * 8; i += 256)
            *(short8v*)&hx2[(i >> 3) * HXS + 32 + (i & 7) * 8] = z;
    }

    const int sx = seq_base + (tid & 63);
    float2 f2;
    {
        const float* rp = is_hist ? &ctx_raw[(size_t)sx * 2]
                                  : &nbr_raw[(size_t)(sx - NB) * 2];
        f2 = *(const float2*)rp;
        const int k0 = (tid >> 6) * 8;
        short8v xv;
#pragma unroll
        for (int u = 0; u < 8; u++) {
            const int xj = k0 + u;
            xv[u] = f2bf(lrelu(ipb[xj] + ipw[xj * 2] * f2.x + ipw[xj * 2 + 1] * f2.y));
        }
        *(short8v*)&hx2[(tid & 63) * HXS + k0] = xv;
    }
    __syncthreads();

    float cst[16];
#pragma unroll
    for (int r = 0; r < 16; r++) cst[r] = 0.0f;

    const int aoff = (M0 + (lane & 31)) * HXS + (lane >> 5) * 8;
    const int hcol = 32 + H * 32 + (lane & 31);

#pragma unroll 1
    for (int t = 0; t < TT; t++) {
        short* cur = hx2 + (t & 1) * (64 * HXS);
        short* nxt = hx2 + ((t + 1) & 1) * (64 * HXS);

        float2 f2n = f2;
        if (t < TT - 1) {
            const float* rp = is_hist
                ? &ctx_raw[((size_t)(t + 1) * NB + sx) * 2]
                : &nbr_raw[((size_t)(t + 1) * NNB + (sx - NB)) * 2];
            f2n = *(const float2*)rp;
        }

        short8v Af[6];
#pragma unroll
        for (int cc = 0; cc < 6; cc++)
            Af[cc] = *(const short8v*)&cur[aoff + cc * 16];

        f32x16 C[4];
#pragma unroll
        for (int gate = 0; gate < 4; gate++)
#pragma unroll
            for (int r = 0; r < 16; r++) C[gate][r] = b4[gate];

#pragma unroll
        for (int cc = 0; cc < 6; cc++)
#pragma unroll
            for (int gate = 0; gate < 4; gate++)
                C[gate] = __builtin_amdgcn_mfma_f32_32x32x16_bf16(
                    Af[cc], Bf[gate][cc], C[gate], 0, 0, 0);

        float hn[16];
#pragma unroll
        for (int r = 0; r < 16; r++) {
            const float iv = sigm2(C[0][r]);
            const float fv = sigm2(C[1][r]);
            const float gv = tanh2(C[2][r]);
            const float ov = sigm2(C[3][r]);
            const float cn = fv * cst[r] + iv * gv;
            cst[r] = cn;
            hn[r] = ov * tanhx(cn);
        }

        if (t < TT - 1) {
#pragma unroll
            for (int r = 0; r < 16; r++) {
                const int row = (r & 3) + 8 * (r >> 2) + 4 * (lane >> 5);
                nxt[(M0 + row) * HXS + hcol] = f2bf(hn[r]);
            }
            const int k0 = (tid >> 6) * 8;
            short8v xv;
#pragma unroll
            for (int u = 0; u < 8; u++) {
                const int xj = k0 + u;
                xv[u] = f2bf(lrelu(ipb[xj] + ipw[xj * 2] * f2n.x + ipw[xj * 2 + 1] * f2n.y));
            }
            *(short8v*)&nxt[(tid & 63) * HXS + k0] = xv;
            __syncthreads();   // single barrier per step
            f2 = f2n;
        } else {
#pragma unroll
            for (int r = 0; r < 16; r++) {
                const int row = (r & 3) + 8 * (r >> 2) + 4 * (lane >> 5);
                hfin[(size_t)(seq_base + M0 + row) * 64 + H * 32 + (lane & 31)] = hn[r];
            }
        }
    }
}

// ===========================================================================
// ATTENTION (unchanged)
// ===========================================================================
__global__ __launch_bounds__(256) void k_attn(
    const float* __restrict__ h_enc,    // [S_TOT][64]
    const float* __restrict__ dynw, const float* __restrict__ dynb,
    const float* __restrict__ l1w,  const float* __restrict__ l1b,
    float* __restrict__ ctx)            // [B][96]
{
    const int b   = blockIdx.x;
    const int tid = threadIdx.x;
    __shared__ float sh_he[32];
    __shared__ float sh_soc[20][65];
    __shared__ float sh_e[20];

    if (tid < 32) {
        float a = dynb[tid];
        const float* w  = &dynw[tid * 64];
        const float* hb = &h_enc[(size_t)b * 64];
#pragma unroll 8
        for (int k = 0; k < 64; k++) a += w[k] * hb[k];
        a = lrelu(a);
        sh_he[tid] = a;
        ctx[b * 96 + tid] = a;
    }
    for (int idx = tid; idx < 20 * 64; idx += 256) {
        const int g = idx >> 6, k = idx & 63;
        sh_soc[g][k] = h_enc[(size_t)(NB + b * 20 + g) * 64 + k];
    }
    __syncthreads();

    if (tid < 20) {
        float e = l1b[0];
#pragma unroll
        for (int m = 0; m < 32; m++) e += l1w[m] * tanhx(sh_he[m]);
#pragma unroll 8
        for (int k = 0; k < 64; k++) e += l1w[32 + k] * tanhx(sh_soc[tid][k]);
        sh_e[tid] = e;
    }
    __syncthreads();

    if (tid < 64) {
        float mx = -1e30f;
#pragma unroll
        for (int g = 0; g < 20; g++) mx = fmaxf(mx, sh_e[g]);
        float wgt[20];
        float sm = 0.0f;
#pragma unroll
        for (int g = 0; g < 20; g++) { wgt[g] = exp2f((sh_e[g] - mx) * L2E); sm += wgt[g]; }
        const float inv = 1.0f / sm;
        float a = 0.0f;
#pragma unroll
        for (int g = 0; g < 20; g++) a += wgt[g] * sh_soc[g][tid];
        ctx[b * 96 + 32 + tid] = a * inv;
    }
}

// ===========================================================================
// DECODER
// ===========================================================================
// Weight pack for 16x16x32 frags: pBd2[hg][kc][frag][lane][8] bf16 where
// frag = nt*4 + gate; B operand: n = lane&15 -> LSTM row gate*256 + hg*32 +
// nt*16 + n; k = kc*32 + (lane>>4)*8 + u. exp2 scale folded.
// opwB2[kc][lane][8]: n = lane&15 -> head output o (zero past 5).
__global__ __launch_bounds__(512) void k_pack_decB2(
    const float* __restrict__ whh,   // (1024,256)
    const float* __restrict__ opw,   // (5,256)
    short* __restrict__ pBd2, short* __restrict__ opwB2)
{
    const int bid  = blockIdx.x;     // 0..63 weights (hg*8+kc); 64..71 head kc
    const int tid  = threadIdx.x;
    const int lane = tid & 63;
    if (bid < 64) {
        const int hg = bid >> 3, kc = bid & 7;
        const int frag = tid >> 6;                // 0..7 = nt*4+gate
        const int nt = frag >> 2, gate = frag & 3;
        const int row = gate * 256 + hg * 32 + nt * 16 + (lane & 15);
        const int kb  = kc * 32 + ((lane >> 4) & 3) * 8;
        const float sc = (gate == 2) ? 2.0f * L2E : L2E;
        short8v v;
#pragma unroll
        for (int u = 0; u < 8; u++) v[u] = f2bf(whh[row * 256 + kb + u] * sc);
        *(short8v*)&pBd2[((size_t)(bid * 8 + frag) * 64 + lane) * 8] = v;
    } else if (tid < 64) {
        const int kc = bid - 64;
        const int n  = lane & 15, kb = kc * 32 + ((lane >> 4) & 3) * 8;
        short8v v;
#pragma unroll
        for (int u = 0; u < 8; u++)
            v[u] = (n < 5) ? f2bf(opw[n * 256 + kb + u]) : (short)0;
        *(short8v*)&opwB2[(kc * 64 + lane) * 8] = v;
    }
}

// Input-gate GEMM -> pgx[agent][j][gate] float4-packed, exp2 scale folded.
__global__ __launch_bounds__(256) void k_gx(
    const float* __restrict__ ctx,
    const float* __restrict__ wih,
    const float* __restrict__ bih, const float* __restrict__ bhh,
    float* __restrict__ pgx)            // [NB][256][4]
{
    const int lane = threadIdx.x & 63;
    const int s    = blockIdx.x * 64 + lane;
    const int jq   = __builtin_amdgcn_readfirstlane(blockIdx.y * 4 + (threadIdx.x >> 6));
    const int j0   = jq * 4;
    float acc[4];
#pragma unroll
    for (int d = 0; d < 4; d++) acc[d] = bih[j0 + d] + bhh[j0 + d];
    const float* c = &ctx[(size_t)s * 96];
    for (int k0 = 0; k0 < 96; k0 += 8) {
        float cb[8];
#pragma unroll
        for (int u = 0; u < 8; u++) cb[u] = c[k0 + u];
#pragma unroll
        for (int d = 0; d < 4; d++) {
            const float* w = &wih[(j0 + d) * 96 + k0];
#pragma unroll
            for (int u = 0; u < 8; u++) acc[d] += w[u] * cb[u];
        }
    }
#pragma unroll
    for (int d = 0; d < 4; d++) {
        const int row = j0 + d;
        const int g = row >> 8, j = row & 255;
        const float sc = (g == 2) ? 2.0f * L2E : L2E;
        pgx[(((size_t)s << 8) + j) * 4 + g] = acc[d] * sc;
    }
}

// stage kc-slice kcv (8 frags x 1KB = 8KB) into wave's LDS buffer bufv
#define STAGE8(kcv, bufv) do {                                             \
    const short* gs = wb + (size_t)(kcv) * 4096 + lane * 8;                \
    short* ls = &wstg[w][bufv][0];                                         \
    gl2lds(gs + 0,    ls + 0);                                             \
    gl2lds(gs + 512,  ls + 512);                                           \
    gl2lds(gs + 1024, ls + 1024);                                          \
    gl2lds(gs + 1536, ls + 1536);                                          \
    gl2lds(gs + 2048, ls + 2048);                                          \
    gl2lds(gs + 2560, ls + 2560);                                          \
    gl2lds(gs + 3072, ls + 3072);                                          \
    gl2lds(gs + 3584, ls + 3584);                                          \
} while (0)

// one kc iteration: wait stage(kcv) landed, ds_read 8 W frags + Af (+Of),
// free buffer (lgkm drain), restage kcv+2, 8(+1) MFMAs.
#define DOCC8(kcv, bufv, VMC, DOSTAGE) do {                                 \
    asm volatile("s_waitcnt vmcnt(" VMC ")" ::: "memory");                  \
    __builtin_amdgcn_sched_barrier(0);                                      \
    const short8v W0 = *(const short8v*)&wstg[w][bufv][0 * 512 + lane * 8]; \
    const short8v W1 = *(const short8v*)&wstg[w][bufv][1 * 512 + lane * 8]; \
    const short8v W2 = *(const short8v*)&wstg[w][bufv][2 * 512 + lane * 8]; \
    const short8v W3 = *(const short8v*)&wstg[w][bufv][3 * 512 + lane * 8]; \
    const short8v W4 = *(const short8v*)&wstg[w][bufv][4 * 512 + lane * 8]; \
    const short8v W5 = *(const short8v*)&wstg[w][bufv][5 * 512 + lane * 8]; \
    const short8v W6 = *(const short8v*)&wstg[w][bufv][6 * 512 + lane * 8]; \
    const short8v W7 = *(const short8v*)&wstg[w][bufv][7 * 512 + lane * 8]; \
    const short8v Af = *(const short8v*)                                    \
        (cur + rowA * 512 + (((kcv) * 64 + kg * 16) ^ ((rowA & 7) << 4)));  \
    short8v Of;                                                             \
    if (headw) Of = *(const short8v*)&ldsO[(kcv) * 512 + lane * 8];         \
    asm volatile("s_waitcnt lgkmcnt(0)" ::: "memory");                      \
    __builtin_amdgcn_sched_barrier(0);                                      \
    if (DOSTAGE) STAGE8((kcv) + 2, bufv);                                   \
    C00 = __builtin_amdgcn_mfma_f32_16x16x32_bf16(Af, W0, C00, 0, 0, 0);    \
    C01 = __builtin_amdgcn_mfma_f32_16x16x32_bf16(Af, W1, C01, 0, 0, 0);    \
    C02 = __builtin_amdgcn_mfma_f32_16x16x32_bf16(Af, W2, C02, 0, 0, 0);    \
    C03 = __builtin_amdgcn_mfma_f32_16x16x32_bf16(Af, W3, C03, 0, 0, 0);    \
    C10 = __builtin_amdgcn_mfma_f32_16x16x32_bf16(Af, W4, C10, 0, 0, 0);    \
    C11 = __builtin_amdgcn_mfma_f32_16x16x32_bf16(Af, W5, C11, 0, 0, 0);    \
    C12 = __builtin_amdgcn_mfma_f32_16x16x32_bf16(Af, W6, C12, 0, 0, 0);    \
    C13 = __builtin_amdgcn_mfma_f32_16x16x32_bf16(Af, W7, C13, 0, 0, 0);    \
    if (headw)                                                              \
        Ch4 = __builtin_amdgcn_mfma_f32_16x16x32_bf16(Af, Of, Ch4, 0, 0, 0);\
} while (0)

// Persistent decoder. 256 blocks x 512 threads; block = 16 agents x all 256
// hidden, wave w = hidden-group w (32 j x 4 gates = 8 16x16 tiles). h
// double-buffered in LDS (bijective column-XOR swizzle). Weights async-
// staged per wave (8KB double buffer, counted vmcnt(8)). Head on wave 0.
__global__ __launch_bounds__(512, 1) void k_dec_persist(
    const float* __restrict__ pgx,    // [NB][256][4]
    const short* __restrict__ pBd2,   // [8][8][8][64][8] bf16
    const short* __restrict__ opwB2,  // [8][64][8] bf16
    const float* __restrict__ opb,
    float* __restrict__ out)
{
    __shared__ short hbuf[2][16 * 256];   // 16 KB
    __shared__ short wstg[8][2][4096];    // 128 KB [wave][buf][frag*512+lane*8]
    __shared__ short ldsO[8 * 512];       // 8 KB   head weights
    const int tid  = threadIdx.x;
    const int lane = tid & 63;
    const int w    = __builtin_amdgcn_readfirstlane(tid >> 6);  // 0..7 = hg
    const int Ab   = blockIdx.x * 16;
    const int rowA = lane & 15;           // agent row within block
    const int kg   = (lane >> 4) & 3;     // k-group 0..3
    const bool headw = (w == 0);

    const short* wb = pBd2 + (size_t)w * 32768;   // wave's weight slice

    // stage head weights once (wave 0 private; its own vmcnt covers it)
    if (headw) {
#pragma unroll
        for (int i = 0; i < 8; i++)
            gl2lds(opwB2 + i * 512 + lane * 8, &ldsO[i * 512]);
    }

    float cst[8];
#pragma unroll
    for (int r = 0; r < 8; r++) cst[r] = 0.0f;

#pragma unroll 1
    for (int t = 0; t < NFUT; t++) {
        const char* cur = (const char*)hbuf[t & 1];
        char* nxt       = (char*)hbuf[(t + 1) & 1];

        f32x4v C00 = {0,0,0,0}, C01 = {0,0,0,0}, C02 = {0,0,0,0}, C03 = {0,0,0,0};
        f32x4v C10 = {0,0,0,0}, C11 = {0,0,0,0}, C12 = {0,0,0,0}, C13 = {0,0,0,0};
        f32x4v Ch4 = {0,0,0,0};

        if (t > 0) {
            STAGE8(0, 0);
            STAGE8(1, 1);
            DOCC8(0, 0, "8", 1);
            DOCC8(1, 1, "8", 1);
            DOCC8(2, 0, "8", 1);
            DOCC8(3, 1, "8", 1);
            DOCC8(4, 0, "8", 1);
            DOCC8(5, 1, "8", 1);
            DOCC8(6, 0, "8", 0);
            DOCC8(7, 1, "0", 0);
        }

        // pointwise: lane owns j = 32w + nt*16 + (lane&15), agents kg*4+r
#pragma unroll
        for (int r = 0; r < 4; r++) {
            const int al = kg * 4 + r;    // local agent (C row = (lane>>4)*4+r)
            {   // nt = 0
                const int j = w * 32 + (lane & 15);
                const float4 g4 = *(const float4*)
                    &pgx[(((size_t)(Ab + al) << 8) + j) * 4];
                const float iv = sigm2(C00[r] + g4.x);
                const float fv = sigm2(C01[r] + g4.y);
                const float gv = tanh2(C02[r] + g4.z);
                const float ov = sigm2(C03[r] + g4.w);
                const float cn = fv * cst[r] + iv * gv;
                cst[r] = cn;
                const int hbyte = al * 512 + ((j * 2) ^ ((al & 7) << 4));
                *(short*)(nxt + hbyte) = f2bf(ov * tanhx(cn));
            }
            {   // nt = 1
                const int j = w * 32 + 16 + (lane & 15);
                const float4 g4 = *(const float4*)
                    &pgx[(((size_t)(Ab + al) << 8) + j) * 4];
                const float iv = sigm2(C10[r] + g4.x);
                const float fv = sigm2(C11[r] + g4.y);
                const float gv = tanh2(C12[r] + g4.z);
                const float ov = sigm2(C13[r] + g4.w);
                const float cn = fv * cst[4 + r] + iv * gv;
                cst[4 + r] = cn;
                const int hbyte = al * 512 + ((j * 2) ^ ((al & 7) << 4));
                *(short*)(nxt + hbyte) = f2bf(ov * tanhx(cn));
            }
        }

        // output head for step t-1 (from h_t = cur); C col = lane&15 = o
        if (t > 0 && headw && (lane & 15) < 5) {
            const int o = lane & 15;
            const float obias = opb[o];
#pragma unroll
            for (int r = 0; r < 4; r++) {
                const int agent = Ab + kg * 4 + r;
                float v = Ch4[r] + obias;
                if (o == 2 || o == 3) v = exp2f(v * L2E);
                else if (o == 4) v = tanhx(v);
                out[(size_t)agent * (NFUT * 5) + (t - 1) * 5 + o] = v;
            }
        }

        __syncthreads();
    }

    // final head: out[23] from h_24 = hbuf[NFUT & 1] (= hbuf[0])
    if (headw) {
        const char* cur = (const char*)hbuf[NFUT & 1];
        f32x4v Ch = {0, 0, 0, 0};
#pragma unroll
        for (int kc = 0; kc < 8; kc++) {
            const int abyte = rowA * 512 + ((kc * 64 + kg * 16) ^ ((rowA & 7) << 4));
            const short8v Af = *(const short8v*)(cur + abyte);
            const short8v Of = *(const short8v*)&ldsO[kc * 512 + lane * 8];
            Ch = __builtin_amdgcn_mfma_f32_16x16x32_bf16(Af, Of, Ch, 0, 0, 0);
        }
        if ((lane & 15) < 5) {
            const int o = lane & 15;
            const float obias = opb[o];
#pragma unroll
            for (int r = 0; r < 4; r++) {
                const int agent = Ab + kg * 4 + r;
                float v = Ch[r] + obias;
                if (o == 2 || o == 3) v = exp2f(v * L2E);
                else if (o == 4) v = tanhx(v);
                out[(size_t)agent * (NFUT * 5) + (NFUT - 1) * 5 + o] = v;
            }
        }
    }
}

extern "C" void kernel_launch(void* const* d_in, const int* in_sizes, int n_in,
                              void* d_out, int out_size, void* d_ws, size_t ws_size,
                              hipStream_t stream)
{
    // 0:x 1:beta 2:context 3:nbrs 4:mask 5:ip_w 6:ip_b 7:enc_wih 8:enc_whh
    // 9:enc_bih 10:enc_bhh 11:dyn_w 12:dyn_b 13:lin1_w 14:lin1_b 15:dec_wih
    // 16:dec_whh 17:dec_bih 18:dec_bhh 19:op_w 20:op_b
    const float* ctx_raw = (const float*)d_in[2];
    const float* nbr_raw = (const float*)d_in[3];
    const float* ipw     = (const float*)d_in[5];
    const float* ipb     = (const float*)d_in[6];
    const float* enc_wih = (const float*)d_in[7];
    const float* enc_whh = (const float*)d_in[8];
    const float* enc_bih = (const float*)d_in[9];
    const float* enc_bhh = (const float*)d_in[10];
    const float* dynw    = (const float*)d_in[11];
    const float* dynb    = (const float*)d_in[12];
    const float* l1w     = (const float*)d_in[13];
    const float* l1b     = (const float*)d_in[14];
    const float* dec_wih = (const float*)d_in[15];
    const float* dec_whh = (const float*)d_in[16];
    const float* dec_bih = (const float*)d_in[17];
    const float* dec_bhh = (const float*)d_in[18];
    const float* opw     = (const float*)d_in[19];
    const float* opb     = (const float*)d_in[20];
    float* out = (float*)d_out;

    // workspace carve-up (~40 MB)
    char* pc = (char*)d_ws;
    float* hfin  = (float*)pc; pc += (size_t)S_TOT * 64 * 4;
    float* ctxb  = (float*)pc; pc += (size_t)NB * 96 * 4;
    float* pgx   = (float*)pc; pc += (size_t)NB * 1024 * 4;
    float* pbias = (float*)pc; pc += 256 * 4;
    short* pB    = (short*)pc; pc += (size_t)48 * 64 * 8 * 2;
    short* pBd2  = (short*)pc; pc += (size_t)64 * 8 * 64 * 8 * 2;
    short* opwB2 = (short*)pc; pc += (size_t)8 * 64 * 8 * 2;

    k_pack_encB<<<dim3(48), 64, 0, stream>>>(enc_wih, enc_whh, enc_bih, enc_bhh,
                                             pB, pbias);
    k_pack_decB2<<<dim3(72), 512, 0, stream>>>(dec_whh, opw, pBd2, opwB2);

    k_encoder<<<dim3(S_TOT / 64), 256, 0, stream>>>(
        ctx_raw, nbr_raw, ipw, ipb, pB, pbias, hfin);

    k_attn<<<dim3(NB), 256, 0, stream>>>(hfin, dynw, dynb, l1w, l1b, ctxb);

    k_gx<<<dim3(NB / 64, 64), 256, 0, stream>>>(ctxb, dec_wih, dec_bih, dec_bhh, pgx);

    k_dec_persist<<<dim3(NB / 16), 512, 0, stream>>>(pgx, pBd2, opwB2, opb, out);
}

// Round 19
// 577.940 us; speedup vs baseline: 1.0888x; 1.0888x over previous
//
#include <hip/hip_runtime.h>

// Social-LSTM trajectory model, FINAL (= v14, measured best: 577 us).
// Encoder LSTM(2->32->64): ONE persistent bf16-MFMA kernel, weights
// register-resident, h/c never leave the CU, double-buffered LDS with one
// barrier per step, exp2/rcp pointwise with log2e folded into weights (261us).
// Decoder LSTM(96->256): ONE persistent kernel (128 blocks x 8 waves; block =
// 32 agents x all 256 hidden), h double-buffered in LDS with bijective
// column-XOR swizzle, weights async-staged per wave via global_load_lds
// (double buffer, counted vmcnt(4)), c in registers, head fused (262us).

#define S_TOT 86016   // 4096 hist + 81920 nbrs
#define NB    4096
#define NNB   81920
#define TT    16
#define NFUT  24
#define HXS   104     // encoder LDS row stride in bf16 (16B-aligned rows)
#define L2E   1.44269504088896f

typedef __attribute__((ext_vector_type(8)))  short short8v;
typedef __attribute__((ext_vector_type(16))) float f32x16;

__device__ __forceinline__ float rcpf(float x) { return __builtin_amdgcn_rcpf(x); }
__device__ __forceinline__ float sigm2(float a)  { return rcpf(1.0f + exp2f(-a)); }
__device__ __forceinline__ float tanh2(float a)  { return 1.0f - 2.0f * rcpf(exp2f(a) + 1.0f); }
__device__ __forceinline__ float tanhx(float x)  { return tanh2(x * (2.0f * L2E)); }
__device__ __forceinline__ float lrelu(float v)  { return v >= 0.0f ? v : 0.1f * v; }
__device__ __forceinline__ short f2bf(float f) {            // RNE fp32->bf16
    unsigned u = __float_as_uint(f);
    unsigned r = (u + 0x7fffu + ((u >> 16) & 1u)) >> 16;
    return (short)r;
}

// async global -> LDS (16B per lane, lds dst wave-uniform base + lane*16)
__device__ __forceinline__ void gl2lds(const short* g, short* l) {
    __builtin_amdgcn_global_load_lds(
        (const __attribute__((address_space(1))) void*)(g),
        (__attribute__((address_space(3))) void*)(l), 16, 0, 0);
}

// ===========================================================================
// ENCODER
// ===========================================================================
__global__ __launch_bounds__(64) void k_pack_encB(
    const float* __restrict__ wih, const float* __restrict__ whh,
    const float* __restrict__ bih, const float* __restrict__ bhh,
    short* __restrict__ pB, float* __restrict__ pbias)
{
    const int fi = blockIdx.x;          // 0..47
    const int cc = fi % 6, gg = fi / 6;
    const int gate = gg & 3, H = gg >> 2;
    const int lane = threadIdx.x;       // 0..63
    const int row  = gate * 64 + H * 32 + (lane & 31);
    const float sc = (gate == 2) ? 2.0f * L2E : L2E;
    short8v v;
#pragma unroll
    for (int u = 0; u < 8; u++) {
        const int k = cc * 16 + (lane >> 5) * 8 + u;
        const float f = (k < 32) ? wih[row * 32 + k] : whh[row * 64 + (k - 32)];
        v[u] = f2bf(f * sc);
    }
    *(short8v*)&pB[((size_t)fi * 64 + lane) * 8] = v;
    if (cc == 0 && lane < 32)
        pbias[H * 128 + gate * 32 + lane] = (bih[row] + bhh[row]) * sc;
}

__global__ __launch_bounds__(256, 2) void k_encoder(
    const float* __restrict__ ctx_raw,  // (T, B, 2)
    const float* __restrict__ nbr_raw,  // (T, N, 2)
    const float* __restrict__ ipw, const float* __restrict__ ipb,
    const short* __restrict__ pB, const float* __restrict__ pbias,
    float* __restrict__ hfin)           // [S_TOT][64]
{
    __shared__ short hx2[2 * 64 * HXS];
    const int tid  = threadIdx.x;
    const int lane = tid & 63;
    const int w    = __builtin_amdgcn_readfirstlane(tid >> 6);  // 0..3
    const int H    = w >> 1;
    const int M0   = (w & 1) * 32;
    const int seq_base = blockIdx.x * 64;
    const bool is_hist = (seq_base < NB);

    short8v Bf[4][6];
#pragma unroll
    for (int gate = 0; gate < 4; gate++)
#pragma unroll
        for (int cc = 0; cc < 6; cc++)
            Bf[gate][cc] = *(const short8v*)
                &pB[(((size_t)(H * 4 + gate) * 6 + cc) * 64 + lane) * 8];

    float b4[4];
#pragma unroll
    for (int gate = 0; gate < 4; gate++)
        b4[gate] = pbias[H * 128 + gate * 32 + (lane & 31)];

    {
        short8v z;
#pragma unroll
        for (int u = 0; u < 8; u++) z[u] = 0;
        for (int i = tid; i < 64 * 8; i += 256)
            *(short8v*)&hx2[(i >> 3) * HXS + 32 + (i & 7) * 8] = z;
    }

    const int sx = seq_base + (tid & 63);
    float2 f2;
    {
        const float* rp = is_hist ? &ctx_raw[(size_t)sx * 2]
                                  : &nbr_raw[(size_t)(sx - NB) * 2];
        f2 = *(const float2*)rp;
        const int k0 = (tid >> 6) * 8;
        short8v xv;
#pragma unroll
        for (int u = 0; u < 8; u++) {
            const int xj = k0 + u;
            xv[u] = f2bf(lrelu(ipb[xj] + ipw[xj * 2] * f2.x + ipw[xj * 2 + 1] * f2.y));
        }
        *(short8v*)&hx2[(tid & 63) * HXS + k0] = xv;
    }
    __syncthreads();

    float cst[16];
#pragma unroll
    for (int r = 0; r < 16; r++) cst[r] = 0.0f;

    const int aoff = (M0 + (lane & 31)) * HXS + (lane >> 5) * 8;
    const int hcol = 32 + H * 32 + (lane & 31);

#pragma unroll 1
    for (int t = 0; t < TT; t++) {
        short* cur = hx2 + (t & 1) * (64 * HXS);
        short* nxt = hx2 + ((t + 1) & 1) * (64 * HXS);

        float2 f2n = f2;
        if (t < TT - 1) {
            const float* rp = is_hist
                ? &ctx_raw[((size_t)(t + 1) * NB + sx) * 2]
                : &nbr_raw[((size_t)(t + 1) * NNB + (sx - NB)) * 2];
            f2n = *(const float2*)rp;
        }

        short8v Af[6];
#pragma unroll
        for (int cc = 0; cc < 6; cc++)
            Af[cc] = *(const short8v*)&cur[aoff + cc * 16];

        f32x16 C[4];
#pragma unroll
        for (int gate = 0; gate < 4; gate++)
#pragma unroll
            for (int r = 0; r < 16; r++) C[gate][r] = b4[gate];

#pragma unroll
        for (int cc = 0; cc < 6; cc++)
#pragma unroll
            for (int gate = 0; gate < 4; gate++)
                C[gate] = __builtin_amdgcn_mfma_f32_32x32x16_bf16(
                    Af[cc], Bf[gate][cc], C[gate], 0, 0, 0);

        float hn[16];
#pragma unroll
        for (int r = 0; r < 16; r++) {
            const float iv = sigm2(C[0][r]);
            const float fv = sigm2(C[1][r]);
            const float gv = tanh2(C[2][r]);
            const float ov = sigm2(C[3][r]);
            const float cn = fv * cst[r] + iv * gv;
            cst[r] = cn;
            hn[r] = ov * tanhx(cn);
        }

        if (t < TT - 1) {
#pragma unroll
            for (int r = 0; r < 16; r++) {
                const int row = (r & 3) + 8 * (r >> 2) + 4 * (lane >> 5);
                nxt[(M0 + row) * HXS + hcol] = f2bf(hn[r]);
            }
            const int k0 = (tid >> 6) * 8;
            short8v xv;
#pragma unroll
            for (int u = 0; u < 8; u++) {
                const int xj = k0 + u;
                xv[u] = f2bf(lrelu(ipb[xj] + ipw[xj * 2] * f2n.x + ipw[xj * 2 + 1] * f2n.y));
            }
            *(short8v*)&nxt[(tid & 63) * HXS + k0] = xv;
            __syncthreads();   // single barrier per step
            f2 = f2n;
        } else {
#pragma unroll
            for (int r = 0; r < 16; r++) {
                const int row = (r & 3) + 8 * (r >> 2) + 4 * (lane >> 5);
                hfin[(size_t)(seq_base + M0 + row) * 64 + H * 32 + (lane & 31)] = hn[r];
            }
        }
    }
}

// ===========================================================================
// ATTENTION
// ===========================================================================
__global__ __launch_bounds__(256) void k_attn(
    const float* __restrict__ h_enc,    // [S_TOT][64]
    const float* __restrict__ dynw, const float* __restrict__ dynb,
    const float* __restrict__ l1w,  const float* __restrict__ l1b,
    float* __restrict__ ctx)            // [B][96]
{
    const int b   = blockIdx.x;
    const int tid = threadIdx.x;
    __shared__ float sh_he[32];
    __shared__ float sh_soc[20][65];
    __shared__ float sh_e[20];

    if (tid < 32) {
        float a = dynb[tid];
        const float* w  = &dynw[tid * 64];
        const float* hb = &h_enc[(size_t)b * 64];
#pragma unroll 8
        for (int k = 0; k < 64; k++) a += w[k] * hb[k];
        a = lrelu(a);
        sh_he[tid] = a;
        ctx[b * 96 + tid] = a;
    }
    for (int idx = tid; idx < 20 * 64; idx += 256) {
        const int g = idx >> 6, k = idx & 63;
        sh_soc[g][k] = h_enc[(size_t)(NB + b * 20 + g) * 64 + k];
    }
    __syncthreads();

    if (tid < 20) {
        float e = l1b[0];
#pragma unroll
        for (int m = 0; m < 32; m++) e += l1w[m] * tanhx(sh_he[m]);
#pragma unroll 8
        for (int k = 0; k < 64; k++) e += l1w[32 + k] * tanhx(sh_soc[tid][k]);
        sh_e[tid] = e;
    }
    __syncthreads();

    if (tid < 64) {
        float mx = -1e30f;
#pragma unroll
        for (int g = 0; g < 20; g++) mx = fmaxf(mx, sh_e[g]);
        float wgt[20];
        float sm = 0.0f;
#pragma unroll
        for (int g = 0; g < 20; g++) { wgt[g] = exp2f((sh_e[g] - mx) * L2E); sm += wgt[g]; }
        const float inv = 1.0f / sm;
        float a = 0.0f;
#pragma unroll
        for (int g = 0; g < 20; g++) a += wgt[g] * sh_soc[g][tid];
        ctx[b * 96 + 32 + tid] = a * inv;
    }
}

// ===========================================================================
// DECODER
// ===========================================================================
__global__ __launch_bounds__(256) void k_pack_decB(
    const float* __restrict__ whh,   // (1024,256)
    const float* __restrict__ opw,   // (5,256)
    short* __restrict__ pBd, short* __restrict__ opwB)
{
    const int bid  = blockIdx.x;     // 0..127 = hg*16+cc ; 128..143 = opw cc
    const int tid  = threadIdx.x;
    const int lane = tid & 63;
    if (bid < 128) {
        const int gate = tid >> 6;
        const int hg = bid >> 4, cc = bid & 15;
        const int row  = gate * 256 + hg * 32 + (lane & 31);
        const int kb   = cc * 16 + (lane >> 5) * 8;
        const float sc = (gate == 2) ? 2.0f * L2E : L2E;
        short8v v;
#pragma unroll
        for (int u = 0; u < 8; u++) v[u] = f2bf(whh[row * 256 + kb + u] * sc);
        *(short8v*)&pBd[((size_t)(bid * 4 + gate) * 64 + lane) * 8] = v;
    } else if (tid < 64) {
        const int cc = bid - 128;
        const int n  = lane & 31, kb = cc * 16 + (lane >> 5) * 8;
        short8v v;
#pragma unroll
        for (int u = 0; u < 8; u++)
            v[u] = (n < 5) ? f2bf(opw[n * 256 + kb + u]) : (short)0;
        *(short8v*)&opwB[(cc * 64 + lane) * 8] = v;
    }
}

// Input-gate GEMM -> pgx[agent][j][gate] float4-packed, exp2 scale folded.
__global__ __launch_bounds__(256) void k_gx(
    const float* __restrict__ ctx,
    const float* __restrict__ wih,
    const float* __restrict__ bih, const float* __restrict__ bhh,
    float* __restrict__ pgx)            // [NB][256][4]
{
    const int lane = threadIdx.x & 63;
    const int s    = blockIdx.x * 64 + lane;
    const int jq   = __builtin_amdgcn_readfirstlane(blockIdx.y * 4 + (threadIdx.x >> 6));
    const int j0   = jq * 4;
    float acc[4];
#pragma unroll
    for (int d = 0; d < 4; d++) acc[d] = bih[j0 + d] + bhh[j0 + d];
    const float* c = &ctx[(size_t)s * 96];
    for (int k0 = 0; k0 < 96; k0 += 8) {
        float cb[8];
#pragma unroll
        for (int u = 0; u < 8; u++) cb[u] = c[k0 + u];
#pragma unroll
        for (int d = 0; d < 4; d++) {
            const float* w = &wih[(j0 + d) * 96 + k0];
#pragma unroll
            for (int u = 0; u < 8; u++) acc[d] += w[u] * cb[u];
        }
    }
#pragma unroll
    for (int d = 0; d < 4; d++) {
        const int row = j0 + d;
        const int g = row >> 8, j = row & 255;
        const float sc = (g == 2) ? 2.0f * L2E : L2E;
        pgx[(((size_t)s << 8) + j) * 4 + g] = acc[d] * sc;
    }
}

// stage cc-group ccv (4 frags x 1KB) into this wave's LDS buffer bufv
#define STAGE(ccv, bufv) do {                                              \
    const short* gs = wb + (size_t)(ccv) * 2048 + lane * 8;                \
    short* ls = &wstg[w][bufv][0];                                         \
    gl2lds(gs + 0,    ls + 0);                                             \
    gl2lds(gs + 512,  ls + 512);                                           \
    gl2lds(gs + 1024, ls + 1024);                                          \
    gl2lds(gs + 1536, ls + 1536);                                          \
} while (0)

// one cc iteration: wait stage(ccv) landed, ds_read frags+Af(+Of), free the
// buffer (lgkm drain), restage ccv+2, MFMA.
#define DOCC(ccv, bufv, VMC, DOSTAGE) do {                                 \
    asm volatile("s_waitcnt vmcnt(" VMC ")" ::: "memory");                 \
    __builtin_amdgcn_sched_barrier(0);                                     \
    const short8v W0 = *(const short8v*)&wstg[w][bufv][0 * 512 + lane * 8];\
    const short8v W1 = *(const short8v*)&wstg[w][bufv][1 * 512 + lane * 8];\
    const short8v W2 = *(const short8v*)&wstg[w][bufv][2 * 512 + lane * 8];\
    const short8v W3 = *(const short8v*)&wstg[w][bufv][3 * 512 + lane * 8];\
    const short8v Af = *(const short8v*)                                   \
        (cur + n * 512 + (((ccv) * 32 + hl * 16) ^ ((n & 7) << 4)));       \
    short8v Of;                                                            \
    if (headw) Of = *(const short8v*)&ldsO[(ccv) * 512 + lane * 8];        \
    asm volatile("s_waitcnt lgkmcnt(0)" ::: "memory");                     \
    __builtin_amdgcn_sched_barrier(0);                                     \
    if (DOSTAGE) STAGE((ccv) + 2, bufv);                                   \
    C[0] = __builtin_amdgcn_mfma_f32_32x32x16_bf16(Af, W0, C[0], 0, 0, 0); \
    C[1] = __builtin_amdgcn_mfma_f32_32x32x16_bf16(Af, W1, C[1], 0, 0, 0); \
    C[2] = __builtin_amdgcn_mfma_f32_32x32x16_bf16(Af, W2, C[2], 0, 0, 0); \
    C[3] = __builtin_amdgcn_mfma_f32_32x32x16_bf16(Af, W3, C[3], 0, 0, 0); \
    if (headw)                                                             \
        Ch = __builtin_amdgcn_mfma_f32_32x32x16_bf16(Af, Of, Ch, 0, 0, 0); \
} while (0)

// Persistent decoder. 128 blocks x 512 threads; block = 32 agents x all 256
// hidden, wave w = hidden-group w. h double-buffered in LDS (bijective
// column-XOR swizzle). Weights async-staged per wave (private LDS double
// buffer, counted vmcnt(4)). c in registers. Head fused on wave 0.
__global__ __launch_bounds__(512, 1) void k_dec_persist(
    const float* __restrict__ pgx,    // [NB][256][4]
    const short* __restrict__ pBd,    // [8][16][4][64][8] bf16
    const short* __restrict__ opwB,   // [16][64][8] bf16
    const float* __restrict__ opb,
    float* __restrict__ out)
{
    __shared__ short hbuf[2][32 * 256];   // 32 KB
    __shared__ short wstg[8][2][2048];    // 64 KB  [wave][buf][frag*512+lane*8]
    __shared__ short ldsO[16 * 512];      // 16 KB  head weights
    const int tid  = threadIdx.x;
    const int lane = tid & 63;
    const int w    = __builtin_amdgcn_readfirstlane(tid >> 6);  // 0..7 = hg
    const int Ab   = blockIdx.x * 32;
    const int n    = lane & 31;
    const int hl   = lane >> 5;           // 0/1
    const bool headw = (w == 0);

    const short* wb = pBd + (size_t)w * 32768;   // wave's weight slice

    // stage head weights once (wave 0's private use; its own vmcnt covers it)
    if (headw) {
#pragma unroll
        for (int i = 0; i < 16; i++)
            gl2lds(opwB + i * 512 + lane * 8, &ldsO[i * 512]);
    }

    float cst[16];
#pragma unroll
    for (int r = 0; r < 16; r++) cst[r] = 0.0f;

#pragma unroll 1
    for (int t = 0; t < NFUT; t++) {
        const char* cur = (const char*)hbuf[t & 1];
        char* nxt       = (char*)hbuf[(t + 1) & 1];

        f32x16 C[4], Ch;
#pragma unroll
        for (int g = 0; g < 4; g++)
#pragma unroll
            for (int r = 0; r < 16; r++) C[g][r] = 0.0f;
#pragma unroll
        for (int r = 0; r < 16; r++) Ch[r] = 0.0f;

        if (t > 0) {
            STAGE(0, 0);
            STAGE(1, 1);
#pragma unroll 1
            for (int c2 = 0; c2 < 14; c2 += 2) {
                DOCC(c2,     0, "4", 1);
                DOCC(c2 + 1, 1, "4", 1);
            }
            DOCC(14, 0, "4", 0);
            DOCC(15, 1, "0", 0);
        }

        // pointwise: lane owns hidden j = 32w+n, 16 agent rows
#pragma unroll
        for (int r = 0; r < 16; r++) {
            const int al = (r & 3) + 8 * (r >> 2) + 4 * hl;   // 0..31
            const float4 g4 = *(const float4*)
                &pgx[(((size_t)(Ab + al) << 8) + w * 32 + n) * 4];
            const float iv = sigm2(C[0][r] + g4.x);
            const float fv = sigm2(C[1][r] + g4.y);
            const float gv = tanh2(C[2][r] + g4.z);
            const float ov = sigm2(C[3][r] + g4.w);
            const float cn = fv * cst[r] + iv * gv;
            cst[r] = cn;
            const int hbyte = al * 512 + (((w * 32 + n) * 2) ^ ((al & 7) << 4));
            *(short*)(nxt + hbyte) = f2bf(ov * tanhx(cn));
        }

        // output head for step t-1 (from h_t = cur)
        if (t > 0 && headw && n < 5) {
            const float obias = opb[n];
#pragma unroll
            for (int r = 0; r < 16; r++) {
                const int agent = Ab + (r & 3) + 8 * (r >> 2) + 4 * hl;
                float v = Ch[r] + obias;
                if (n == 2 || n == 3) v = exp2f(v * L2E);
                else if (n == 4) v = tanhx(v);
                out[(size_t)agent * (NFUT * 5) + (t - 1) * 5 + n] = v;
            }
        }

        __syncthreads();
    }

    // final head: out[23] from h_24 = hbuf[NFUT & 1] (= hbuf[0])
    if (headw) {
        const char* cur = (const char*)hbuf[NFUT & 1];
        f32x16 Ch;
#pragma unroll
        for (int r = 0; r < 16; r++) Ch[r] = 0.0f;
#pragma unroll 4
        for (int cc = 0; cc < 16; cc++) {
            const int abyte = n * 512 + ((cc * 32 + hl * 16) ^ ((n & 7) << 4));
            const short8v Af = *(const short8v*)(cur + abyte);
            const short8v Of = *(const short8v*)&ldsO[cc * 512 + lane * 8];
            Ch = __builtin_amdgcn_mfma_f32_32x32x16_bf16(Af, Of, Ch, 0, 0, 0);
        }
        if (n < 5) {
            const float obias = opb[n];
#pragma unroll
            for (int r = 0; r < 16; r++) {
                const int agent = Ab + (r & 3) + 8 * (r >> 2) + 4 * hl;
                float v = Ch[r] + obias;
                if (n == 2 || n == 3) v = exp2f(v * L2E);
                else if (n == 4) v = tanhx(v);
                out[(size_t)agent * (NFUT * 5) + (NFUT - 1) * 5 + n] = v;
            }
        }
    }
}

extern "C" void kernel_launch(void* const* d_in, const int* in_sizes, int n_in,
                              void* d_out, int out_size, void* d_ws, size_t ws_size,
                              hipStream_t stream)
{
    // 0:x 1:beta 2:context 3:nbrs 4:mask 5:ip_w 6:ip_b 7:enc_wih 8:enc_whh
    // 9:enc_bih 10:enc_bhh 11:dyn_w 12:dyn_b 13:lin1_w 14:lin1_b 15:dec_wih
    // 16:dec_whh 17:dec_bih 18:dec_bhh 19:op_w 20:op_b
    const float* ctx_raw = (const float*)d_in[2];
    const float* nbr_raw = (const float*)d_in[3];
    const float* ipw     = (const float*)d_in[5];
    const float* ipb     = (const float*)d_in[6];
    const float* enc_wih = (const float*)d_in[7];
    const float* enc_whh = (const float*)d_in[8];
    const float* enc_bih = (const float*)d_in[9];
    const float* enc_bhh = (const float*)d_in[10];
    const float* dynw    = (const float*)d_in[11];
    const float* dynb    = (const float*)d_in[12];
    const float* l1w     = (const float*)d_in[13];
    const float* l1b     = (const float*)d_in[14];
    const float* dec_wih = (const float*)d_in[15];
    const float* dec_whh = (const float*)d_in[16];
    const float* dec_bih = (const float*)d_in[17];
    const float* dec_bhh = (const float*)d_in[18];
    const float* opw     = (const float*)d_in[19];
    const float* opb     = (const float*)d_in[20];
    float* out = (float*)d_out;

    // workspace carve-up (~40 MB)
    char* pc = (char*)d_ws;
    float* hfin  = (float*)pc; pc += (size_t)S_TOT * 64 * 4;
    float* ctxb  = (float*)pc; pc += (size_t)NB * 96 * 4;
    float* pgx   = (float*)pc; pc += (size_t)NB * 1024 * 4;
    float* pbias = (float*)pc; pc += 256 * 4;
    short* pB    = (short*)pc; pc += (size_t)48 * 64 * 8 * 2;
    short* pBd   = (short*)pc; pc += (size_t)8 * 16 * 4 * 64 * 8 * 2;
    short* opwB  = (short*)pc; pc += (size_t)16 * 64 * 8 * 2;

    k_pack_encB<<<dim3(48), 64, 0, stream>>>(enc_wih, enc_whh, enc_bih, enc_bhh,
                                             pB, pbias);
    k_pack_decB<<<dim3(144), 256, 0, stream>>>(dec_whh, opw, pBd, opwB);

    k_encoder<<<dim3(S_TOT / 64), 256, 0, stream>>>(
        ctx_raw, nbr_raw, ipw, ipb, pB, pbias, hfin);

    k_attn<<<dim3(NB), 256, 0, stream>>>(hfin, dynw, dynb, l1w, l1b, ctxb);

    k_gx<<<dim3(NB / 64, 64), 256, 0, stream>>>(ctxb, dec_wih, dec_bih, dec_bhh, pgx);

    k_dec_persist<<<dim3(NB / 32), 512, 0, stream>>>(pgx, pBd, opwB, opb, out);
}

// Round 20
// 566.132 us; speedup vs baseline: 1.1115x; 1.0209x over previous
//
#include <hip/hip_runtime.h>

// Social-LSTM trajectory model, v19 (= v14 + fused-reciprocal pointwise:
// i*g and o*tanh(c) each share ONE v_rcp -> 5 rcp/elem -> 3 rcp/elem).
// Encoder LSTM(2->32->64): ONE persistent bf16-MFMA kernel (was 261us).
// Decoder LSTM(96->256): ONE persistent kernel, async global_load_lds
// double-buffered weight staging, counted vmcnt(4) (was 262us).

#define S_TOT 86016   // 4096 hist + 81920 nbrs
#define NB    4096
#define NNB   81920
#define TT    16
#define NFUT  24
#define HXS   104     // encoder LDS row stride in bf16 (16B-aligned rows)
#define L2E   1.44269504088896f

typedef __attribute__((ext_vector_type(8)))  short short8v;
typedef __attribute__((ext_vector_type(16))) float f32x16;

__device__ __forceinline__ float rcpf(float x) { return __builtin_amdgcn_rcpf(x); }
__device__ __forceinline__ float sigm2(float a)  { return rcpf(1.0f + exp2f(-a)); }
__device__ __forceinline__ float tanh2(float a)  { return 1.0f - 2.0f * rcpf(exp2f(a) + 1.0f); }
__device__ __forceinline__ float tanhx(float x)  { return tanh2(x * (2.0f * L2E)); }
__device__ __forceinline__ float lrelu(float v)  { return v >= 0.0f ? v : 0.1f * v; }
__device__ __forceinline__ short f2bf(float f) {            // RNE fp32->bf16
    unsigned u = __float_as_uint(f);
    unsigned r = (u + 0x7fffu + ((u >> 16) & 1u)) >> 16;
    return (short)r;
}

// async global -> LDS (16B per lane, lds dst wave-uniform base + lane*16)
__device__ __forceinline__ void gl2lds(const short* g, short* l) {
    __builtin_amdgcn_global_load_lds(
        (const __attribute__((address_space(1))) void*)(g),
        (__attribute__((address_space(3))) void*)(l), 16, 0, 0);
}

// ===========================================================================
// ENCODER
// ===========================================================================
__global__ __launch_bounds__(64) void k_pack_encB(
    const float* __restrict__ wih, const float* __restrict__ whh,
    const float* __restrict__ bih, const float* __restrict__ bhh,
    short* __restrict__ pB, float* __restrict__ pbias)
{
    const int fi = blockIdx.x;          // 0..47
    const int cc = fi % 6, gg = fi / 6;
    const int gate = gg & 3, H = gg >> 2;
    const int lane = threadIdx.x;       // 0..63
    const int row  = gate * 64 + H * 32 + (lane & 31);
    const float sc = (gate == 2) ? 2.0f * L2E : L2E;
    short8v v;
#pragma unroll
    for (int u = 0; u < 8; u++) {
        const int k = cc * 16 + (lane >> 5) * 8 + u;
        const float f = (k < 32) ? wih[row * 32 + k] : whh[row * 64 + (k - 32)];
        v[u] = f2bf(f * sc);
    }
    *(short8v*)&pB[((size_t)fi * 64 + lane) * 8] = v;
    if (cc == 0 && lane < 32)
        pbias[H * 128 + gate * 32 + lane] = (bih[row] + bhh[row]) * sc;
}

__global__ __launch_bounds__(256, 2) void k_encoder(
    const float* __restrict__ ctx_raw,  // (T, B, 2)
    const float* __restrict__ nbr_raw,  // (T, N, 2)
    const float* __restrict__ ipw, const float* __restrict__ ipb,
    const short* __restrict__ pB, const float* __restrict__ pbias,
    float* __restrict__ hfin)           // [S_TOT][64]
{
    __shared__ short hx2[2 * 64 * HXS];
    const int tid  = threadIdx.x;
    const int lane = tid & 63;
    const int w    = __builtin_amdgcn_readfirstlane(tid >> 6);  // 0..3
    const int H    = w >> 1;
    const int M0   = (w & 1) * 32;
    const int seq_base = blockIdx.x * 64;
    const bool is_hist = (seq_base < NB);

    short8v Bf[4][6];
#pragma unroll
    for (int gate = 0; gate < 4; gate++)
#pragma unroll
        for (int cc = 0; cc < 6; cc++)
            Bf[gate][cc] = *(const short8v*)
                &pB[(((size_t)(H * 4 + gate) * 6 + cc) * 64 + lane) * 8];

    float b4[4];
#pragma unroll
    for (int gate = 0; gate < 4; gate++)
        b4[gate] = pbias[H * 128 + gate * 32 + (lane & 31)];

    {
        short8v z;
#pragma unroll
        for (int u = 0; u < 8; u++) z[u] = 0;
        for (int i = tid; i < 64 * 8; i += 256)
            *(short8v*)&hx2[(i >> 3) * HXS + 32 + (i & 7) * 8] = z;
    }

    const int sx = seq_base + (tid & 63);
    float2 f2;
    {
        const float* rp = is_hist ? &ctx_raw[(size_t)sx * 2]
                                  : &nbr_raw[(size_t)(sx - NB) * 2];
        f2 = *(const float2*)rp;
        const int k0 = (tid >> 6) * 8;
        short8v xv;
#pragma unroll
        for (int u = 0; u < 8; u++) {
            const int xj = k0 + u;
            xv[u] = f2bf(lrelu(ipb[xj] + ipw[xj * 2] * f2.x + ipw[xj * 2 + 1] * f2.y));
        }
        *(short8v*)&hx2[(tid & 63) * HXS + k0] = xv;
    }
    __syncthreads();

    float cst[16];
#pragma unroll
    for (int r = 0; r < 16; r++) cst[r] = 0.0f;

    const int aoff = (M0 + (lane & 31)) * HXS + (lane >> 5) * 8;
    const int hcol = 32 + H * 32 + (lane & 31);

#pragma unroll 1
    for (int t = 0; t < TT; t++) {
        short* cur = hx2 + (t & 1) * (64 * HXS);
        short* nxt = hx2 + ((t + 1) & 1) * (64 * HXS);

        float2 f2n = f2;
        if (t < TT - 1) {
            const float* rp = is_hist
                ? &ctx_raw[((size_t)(t + 1) * NB + sx) * 2]
                : &nbr_raw[((size_t)(t + 1) * NNB + (sx - NB)) * 2];
            f2n = *(const float2*)rp;
        }

        short8v Af[6];
#pragma unroll
        for (int cc = 0; cc < 6; cc++)
            Af[cc] = *(const short8v*)&cur[aoff + cc * 16];

        f32x16 C[4];
#pragma unroll
        for (int gate = 0; gate < 4; gate++)
#pragma unroll
            for (int r = 0; r < 16; r++) C[gate][r] = b4[gate];

#pragma unroll
        for (int cc = 0; cc < 6; cc++)
#pragma unroll
            for (int gate = 0; gate < 4; gate++)
                C[gate] = __builtin_amdgcn_mfma_f32_32x32x16_bf16(
                    Af[cc], Bf[gate][cc], C[gate], 0, 0, 0);

        // pointwise, fused reciprocals: i*g and o*tanh(c) share one rcp each
        float hn[16];
#pragma unroll
        for (int r = 0; r < 16; r++) {
            const float ei = exp2f(-C[0][r]);
            const float ef = exp2f(-C[1][r]);
            const float eg = exp2f(C[2][r]);
            const float eo = exp2f(-C[3][r]);
            const float ivgv = (eg - 1.0f) * rcpf((1.0f + ei) * (eg + 1.0f));
            const float cn = cst[r] * rcpf(1.0f + ef) + ivgv;
            cst[r] = cn;
            const float ec = exp2f(cn * (2.0f * L2E));
            hn[r] = (ec - 1.0f) * rcpf((1.0f + eo) * (ec + 1.0f));
        }

        if (t < TT - 1) {
#pragma unroll
            for (int r = 0; r < 16; r++) {
                const int row = (r & 3) + 8 * (r >> 2) + 4 * (lane >> 5);
                nxt[(M0 + row) * HXS + hcol] = f2bf(hn[r]);
            }
            const int k0 = (tid >> 6) * 8;
            short8v xv;
#pragma unroll
            for (int u = 0; u < 8; u++) {
                const int xj = k0 + u;
                xv[u] = f2bf(lrelu(ipb[xj] + ipw[xj * 2] * f2n.x + ipw[xj * 2 + 1] * f2n.y));
            }
            *(short8v*)&nxt[(tid & 63) * HXS + k0] = xv;
            __syncthreads();   // single barrier per step
            f2 = f2n;
        } else {
#pragma unroll
            for (int r = 0; r < 16; r++) {
                const int row = (r & 3) + 8 * (r >> 2) + 4 * (lane >> 5);
                hfin[(size_t)(seq_base + M0 + row) * 64 + H * 32 + (lane & 31)] = hn[r];
            }
        }
    }
}

// ===========================================================================
// ATTENTION (unchanged)
// ===========================================================================
__global__ __launch_bounds__(256) void k_attn(
    const float* __restrict__ h_enc,    // [S_TOT][64]
    const float* __restrict__ dynw, const float* __restrict__ dynb,
    const float* __restrict__ l1w,  const float* __restrict__ l1b,
    float* __restrict__ ctx)            // [B][96]
{
    const int b   = blockIdx.x;
    const int tid = threadIdx.x;
    __shared__ float sh_he[32];
    __shared__ float sh_soc[20][65];
    __shared__ float sh_e[20];

    if (tid < 32) {
        float a = dynb[tid];
        const float* w  = &dynw[tid * 64];
        const float* hb = &h_enc[(size_t)b * 64];
#pragma unroll 8
        for (int k = 0; k < 64; k++) a += w[k] * hb[k];
        a = lrelu(a);
        sh_he[tid] = a;
        ctx[b * 96 + tid] = a;
    }
    for (int idx = tid; idx < 20 * 64; idx += 256) {
        const int g = idx >> 6, k = idx & 63;
        sh_soc[g][k] = h_enc[(size_t)(NB + b * 20 + g) * 64 + k];
    }
    __syncthreads();

    if (tid < 20) {
        float e = l1b[0];
#pragma unroll
        for (int m = 0; m < 32; m++) e += l1w[m] * tanhx(sh_he[m]);
#pragma unroll 8
        for (int k = 0; k < 64; k++) e += l1w[32 + k] * tanhx(sh_soc[tid][k]);
        sh_e[tid] = e;
    }
    __syncthreads();

    if (tid < 64) {
        float mx = -1e30f;
#pragma unroll
        for (int g = 0; g < 20; g++) mx = fmaxf(mx, sh_e[g]);
        float wgt[20];
        float sm = 0.0f;
#pragma unroll
        for (int g = 0; g < 20; g++) { wgt[g] = exp2f((sh_e[g] - mx) * L2E); sm += wgt[g]; }
        const float inv = 1.0f / sm;
        float a = 0.0f;
#pragma unroll
        for (int g = 0; g < 20; g++) a += wgt[g] * sh_soc[g][tid];
        ctx[b * 96 + 32 + tid] = a * inv;
    }
}

// ===========================================================================
// DECODER
// ===========================================================================
__global__ __launch_bounds__(256) void k_pack_decB(
    const float* __restrict__ whh,   // (1024,256)
    const float* __restrict__ opw,   // (5,256)
    short* __restrict__ pBd, short* __restrict__ opwB)
{
    const int bid  = blockIdx.x;     // 0..127 = hg*16+cc ; 128..143 = opw cc
    const int tid  = threadIdx.x;
    const int lane = tid & 63;
    if (bid < 128) {
        const int gate = tid >> 6;
        const int hg = bid >> 4, cc = bid & 15;
        const int row  = gate * 256 + hg * 32 + (lane & 31);
        const int kb   = cc * 16 + (lane >> 5) * 8;
        const float sc = (gate == 2) ? 2.0f * L2E : L2E;
        short8v v;
#pragma unroll
        for (int u = 0; u < 8; u++) v[u] = f2bf(whh[row * 256 + kb + u] * sc);
        *(short8v*)&pBd[((size_t)(bid * 4 + gate) * 64 + lane) * 8] = v;
    } else if (tid < 64) {
        const int cc = bid - 128;
        const int n  = lane & 31, kb = cc * 16 + (lane >> 5) * 8;
        short8v v;
#pragma unroll
        for (int u = 0; u < 8; u++)
            v[u] = (n < 5) ? f2bf(opw[n * 256 + kb + u]) : (short)0;
        *(short8v*)&opwB[(cc * 64 + lane) * 8] = v;
    }
}

// Input-gate GEMM -> pgx[agent][j][gate] float4-packed, exp2 scale folded.
__global__ __launch_bounds__(256) void k_gx(
    const float* __restrict__ ctx,
    const float* __restrict__ wih,
    const float* __restrict__ bih, const float* __restrict__ bhh,
    float* __restrict__ pgx)            // [NB][256][4]
{
    const int lane = threadIdx.x & 63;
    const int s    = blockIdx.x * 64 + lane;
    const int jq   = __builtin_amdgcn_readfirstlane(blockIdx.y * 4 + (threadIdx.x >> 6));
    const int j0   = jq * 4;
    float acc[4];
#pragma unroll
    for (int d = 0; d < 4; d++) acc[d] = bih[j0 + d] + bhh[j0 + d];
    const float* c = &ctx[(size_t)s * 96];
    for (int k0 = 0; k0 < 96; k0 += 8) {
        float cb[8];
#pragma unroll
        for (int u = 0; u < 8; u++) cb[u] = c[k0 + u];
#pragma unroll
        for (int d = 0; d < 4; d++) {
            const float* w = &wih[(j0 + d) * 96 + k0];
#pragma unroll
            for (int u = 0; u < 8; u++) acc[d] += w[u] * cb[u];
        }
    }
#pragma unroll
    for (int d = 0; d < 4; d++) {
        const int row = j0 + d;
        const int g = row >> 8, j = row & 255;
        const float sc = (g == 2) ? 2.0f * L2E : L2E;
        pgx[(((size_t)s << 8) + j) * 4 + g] = acc[d] * sc;
    }
}

// stage cc-group ccv (4 frags x 1KB) into this wave's LDS buffer bufv
#define STAGE(ccv, bufv) do {                                              \
    const short* gs = wb + (size_t)(ccv) * 2048 + lane * 8;                \
    short* ls = &wstg[w][bufv][0];                                         \
    gl2lds(gs + 0,    ls + 0);                                             \
    gl2lds(gs + 512,  ls + 512);                                           \
    gl2lds(gs + 1024, ls + 1024);                                          \
    gl2lds(gs + 1536, ls + 1536);                                          \
} while (0)

// one cc iteration: wait stage(ccv) landed, ds_read frags+Af(+Of), free the
// buffer (lgkm drain), restage ccv+2, MFMA.
#define DOCC(ccv, bufv, VMC, DOSTAGE) do {                                 \
    asm volatile("s_waitcnt vmcnt(" VMC ")" ::: "memory");                 \
    __builtin_amdgcn_sched_barrier(0);                                     \
    const short8v W0 = *(const short8v*)&wstg[w][bufv][0 * 512 + lane * 8];\
    const short8v W1 = *(const short8v*)&wstg[w][bufv][1 * 512 + lane * 8];\
    const short8v W2 = *(const short8v*)&wstg[w][bufv][2 * 512 + lane * 8];\
    const short8v W3 = *(const short8v*)&wstg[w][bufv][3 * 512 + lane * 8];\
    const short8v Af = *(const short8v*)                                   \
        (cur + n * 512 + (((ccv) * 32 + hl * 16) ^ ((n & 7) << 4)));       \
    short8v Of;                                                            \
    if (headw) Of = *(const short8v*)&ldsO[(ccv) * 512 + lane * 8];        \
    asm volatile("s_waitcnt lgkmcnt(0)" ::: "memory");                     \
    __builtin_amdgcn_sched_barrier(0);                                     \
    if (DOSTAGE) STAGE((ccv) + 2, bufv);                                   \
    C[0] = __builtin_amdgcn_mfma_f32_32x32x16_bf16(Af, W0, C[0], 0, 0, 0); \
    C[1] = __builtin_amdgcn_mfma_f32_32x32x16_bf16(Af, W1, C[1], 0, 0, 0); \
    C[2] = __builtin_amdgcn_mfma_f32_32x32x16_bf16(Af, W2, C[2], 0, 0, 0); \
    C[3] = __builtin_amdgcn_mfma_f32_32x32x16_bf16(Af, W3, C[3], 0, 0, 0); \
    if (headw)                                                             \
        Ch = __builtin_amdgcn_mfma_f32_32x32x16_bf16(Af, Of, Ch, 0, 0, 0); \
} while (0)

// Persistent decoder. 128 blocks x 512 threads; block = 32 agents x all 256
// hidden, wave w = hidden-group w. h double-buffered in LDS (bijective
// column-XOR swizzle). Weights async-staged per wave (private LDS double
// buffer, counted vmcnt(4)). c in registers. Head fused on wave 0.
__global__ __launch_bounds__(512, 1) void k_dec_persist(
    const float* __restrict__ pgx,    // [NB][256][4]
    const short* __restrict__ pBd,    // [8][16][4][64][8] bf16
    const short* __restrict__ opwB,   // [16][64][8] bf16
    const float* __restrict__ opb,
    float* __restrict__ out)
{
    __shared__ short hbuf[2][32 * 256];   // 32 KB
    __shared__ short wstg[8][2][2048];    // 64 KB  [wave][buf][frag*512+lane*8]
    __shared__ short ldsO[16 * 512];      // 16 KB  head weights
    const int tid  = threadIdx.x;
    const int lane = tid & 63;
    const int w    = __builtin_amdgcn_readfirstlane(tid >> 6);  // 0..7 = hg
    const int Ab   = blockIdx.x * 32;
    const int n    = lane & 31;
    const int hl   = lane >> 5;           // 0/1
    const bool headw = (w == 0);

    const short* wb = pBd + (size_t)w * 32768;   // wave's weight slice

    // stage head weights once (wave 0's private use; its own vmcnt covers it)
    if (headw) {
#pragma unroll
        for (int i = 0; i < 16; i++)
            gl2lds(opwB + i * 512 + lane * 8, &ldsO[i * 512]);
    }

    float cst[16];
#pragma unroll
    for (int r = 0; r < 16; r++) cst[r] = 0.0f;

#pragma unroll 1
    for (int t = 0; t < NFUT; t++) {
        const char* cur = (const char*)hbuf[t & 1];
        char* nxt       = (char*)hbuf[(t + 1) & 1];

        f32x16 C[4], Ch;
#pragma unroll
        for (int g = 0; g < 4; g++)
#pragma unroll
            for (int r = 0; r < 16; r++) C[g][r] = 0.0f;
#pragma unroll
        for (int r = 0; r < 16; r++) Ch[r] = 0.0f;

        if (t > 0) {
            STAGE(0, 0);
            STAGE(1, 1);
#pragma unroll 1
            for (int c2 = 0; c2 < 14; c2 += 2) {
                DOCC(c2,     0, "4", 1);
                DOCC(c2 + 1, 1, "4", 1);
            }
            DOCC(14, 0, "4", 0);
            DOCC(15, 1, "0", 0);
        }

        // pointwise (fused reciprocals): lane owns j = 32w+n, 16 agent rows
#pragma unroll
        for (int r = 0; r < 16; r++) {
            const int al = (r & 3) + 8 * (r >> 2) + 4 * hl;   // 0..31
            const float4 g4 = *(const float4*)
                &pgx[(((size_t)(Ab + al) << 8) + w * 32 + n) * 4];
            const float ei = exp2f(-(C[0][r] + g4.x));
            const float ef = exp2f(-(C[1][r] + g4.y));
            const float eg = exp2f(C[2][r] + g4.z);
            const float eo = exp2f(-(C[3][r] + g4.w));
            const float ivgv = (eg - 1.0f) * rcpf((1.0f + ei) * (eg + 1.0f));
            const float cn = cst[r] * rcpf(1.0f + ef) + ivgv;
            cst[r] = cn;
            const float ec = exp2f(cn * (2.0f * L2E));
            const float hv = (ec - 1.0f) * rcpf((1.0f + eo) * (ec + 1.0f));
            const int hbyte = al * 512 + (((w * 32 + n) * 2) ^ ((al & 7) << 4));
            *(short*)(nxt + hbyte) = f2bf(hv);
        }

        // output head for step t-1 (from h_t = cur)
        if (t > 0 && headw && n < 5) {
            const float obias = opb[n];
#pragma unroll
            for (int r = 0; r < 16; r++) {
                const int agent = Ab + (r & 3) + 8 * (r >> 2) + 4 * hl;
                float v = Ch[r] + obias;
                if (n == 2 || n == 3) v = exp2f(v * L2E);
                else if (n == 4) v = tanhx(v);
                out[(size_t)agent * (NFUT * 5) + (t - 1) * 5 + n] = v;
            }
        }

        __syncthreads();
    }

    // final head: out[23] from h_24 = hbuf[NFUT & 1] (= hbuf[0])
    if (headw) {
        const char* cur = (const char*)hbuf[NFUT & 1];
        f32x16 Ch;
#pragma unroll
        for (int r = 0; r < 16; r++) Ch[r] = 0.0f;
#pragma unroll 4
        for (int cc = 0; cc < 16; cc++) {
            const int abyte = n * 512 + ((cc * 32 + hl * 16) ^ ((n & 7) << 4));
            const short8v Af = *(const short8v*)(cur + abyte);
            const short8v Of = *(const short8v*)&ldsO[cc * 512 + lane * 8];
            Ch = __builtin_amdgcn_mfma_f32_32x32x16_bf16(Af, Of, Ch, 0, 0, 0);
        }
        if (n < 5) {
            const float obias = opb[n];
#pragma unroll
            for (int r = 0; r < 16; r++) {
                const int agent = Ab + (r & 3) + 8 * (r >> 2) + 4 * hl;
                float v = Ch[r] + obias;
                if (n == 2 || n == 3) v = exp2f(v * L2E);
                else if (n == 4) v = tanhx(v);
                out[(size_t)agent * (NFUT * 5) + (NFUT - 1) * 5 + n] = v;
            }
        }
    }
}

extern "C" void kernel_launch(void* const* d_in, const int* in_sizes, int n_in,
                              void* d_out, int out_size, void* d_ws, size_t ws_size,
                              hipStream_t stream)
{
    // 0:x 1:beta 2:context 3:nbrs 4:mask 5:ip_w 6:ip_b 7:enc_wih 8:enc_whh
    // 9:enc_bih 10:enc_bhh 11:dyn_w 12:dyn_b 13:lin1_w 14:lin1_b 15:dec_wih
    // 16:dec_whh 17:dec_bih 18:dec_bhh 19:op_w 20:op_b
    const float* ctx_raw = (const float*)d_in[2];
    const float* nbr_raw = (const float*)d_in[3];
    const float* ipw     = (const float*)d_in[5];
    const float* ipb     = (const float*)d_in[6];
    const float* enc_wih = (const float*)d_in[7];
    const float* enc_whh = (const float*)d_in[8];
    const float* enc_bih = (const float*)d_in[9];
    const float* enc_bhh = (const float*)d_in[10];
    const float* dynw    = (const float*)d_in[11];
    const float* dynb    = (const float*)d_in[12];
    const float* l1w     = (const float*)d_in[13];
    const float* l1b     = (const float*)d_in[14];
    const float* dec_wih = (const float*)d_in[15];
    const float* dec_whh = (const float*)d_in[16];
    const float* dec_bih = (const float*)d_in[17];
    const float* dec_bhh = (const float*)d_in[18];
    const float* opw     = (const float*)d_in[19];
    const float* opb     = (const float*)d_in[20];
    float* out = (float*)d_out;

    // workspace carve-up (~40 MB)
    char* pc = (char*)d_ws;
    float* hfin  = (float*)pc; pc += (size_t)S_TOT * 64 * 4;
    float* ctxb  = (float*)pc; pc += (size_t)NB * 96 * 4;
    float* pgx   = (float*)pc; pc += (size_t)NB * 1024 * 4;
    float* pbias = (float*)pc; pc += 256 * 4;
    short* pB    = (short*)pc; pc += (size_t)48 * 64 * 8 * 2;
    short* pBd   = (short*)pc; pc += (size_t)8 * 16 * 4 * 64 * 8 * 2;
    short* opwB  = (short*)pc; pc += (size_t)16 * 64 * 8 * 2;

    k_pack_encB<<<dim3(48), 64, 0, stream>>>(enc_wih, enc_whh, enc_bih, enc_bhh,
                                             pB, pbias);
    k_pack_decB<<<dim3(144), 256, 0, stream>>>(dec_whh, opw, pBd, opwB);

    k_encoder<<<dim3(S_TOT / 64), 256, 0, stream>>>(
        ctx_raw, nbr_raw, ipw, ipb, pB, pbias, hfin);

    k_attn<<<dim3(NB), 256, 0, stream>>>(hfin, dynw, dynb, l1w, l1b, ctxb);

    k_gx<<<dim3(NB / 64, 64), 256, 0, stream>>>(ctxb, dec_wih, dec_bih, dec_bhh, pgx);

    k_dec_persist<<<dim3(NB / 32), 512, 0, stream>>>(pgx, pBd, opwB, opb, out);
}

// Round 21
// 565.923 us; speedup vs baseline: 1.1119x; 1.0004x over previous
//
#include <hip/hip_runtime.h>

// Social-LSTM trajectory model, FINAL (v19, measured best: 566 us).
// Encoder LSTM(2->32->64): ONE persistent bf16-MFMA kernel, weights
// register-resident, h/c never leave the CU, double-buffered LDS with one
// barrier per step, exp2/rcp pointwise with log2e folded into weights and
// fused reciprocals (i*g and o*tanh(c) share one v_rcp each). ~259 us.
// Decoder LSTM(96->256): ONE persistent kernel (128 blocks x 8 waves; block =
// 32 agents x all 256 hidden), h double-buffered in LDS with bijective
// column-XOR swizzle, weights async-staged per wave via global_load_lds
// (double buffer, counted vmcnt(4)), c in registers, head fused. ~257 us.

#define S_TOT 86016   // 4096 hist + 81920 nbrs
#define NB    4096
#define NNB   81920
#define TT    16
#define NFUT  24
#define HXS   104     // encoder LDS row stride in bf16 (16B-aligned rows)
#define L2E   1.44269504088896f

typedef __attribute__((ext_vector_type(8)))  short short8v;
typedef __attribute__((ext_vector_type(16))) float f32x16;

__device__ __forceinline__ float rcpf(float x) { return __builtin_amdgcn_rcpf(x); }
__device__ __forceinline__ float sigm2(float a)  { return rcpf(1.0f + exp2f(-a)); }
__device__ __forceinline__ float tanh2(float a)  { return 1.0f - 2.0f * rcpf(exp2f(a) + 1.0f); }
__device__ __forceinline__ float tanhx(float x)  { return tanh2(x * (2.0f * L2E)); }
__device__ __forceinline__ float lrelu(float v)  { return v >= 0.0f ? v : 0.1f * v; }
__device__ __forceinline__ short f2bf(float f) {            // RNE fp32->bf16
    unsigned u = __float_as_uint(f);
    unsigned r = (u + 0x7fffu + ((u >> 16) & 1u)) >> 16;
    return (short)r;
}

// async global -> LDS (16B per lane, lds dst wave-uniform base + lane*16)
__device__ __forceinline__ void gl2lds(const short* g, short* l) {
    __builtin_amdgcn_global_load_lds(
        (const __attribute__((address_space(1))) void*)(g),
        (__attribute__((address_space(3))) void*)(l), 16, 0, 0);
}

// ===========================================================================
// ENCODER
// ===========================================================================
__global__ __launch_bounds__(64) void k_pack_encB(
    const float* __restrict__ wih, const float* __restrict__ whh,
    const float* __restrict__ bih, const float* __restrict__ bhh,
    short* __restrict__ pB, float* __restrict__ pbias)
{
    const int fi = blockIdx.x;          // 0..47
    const int cc = fi % 6, gg = fi / 6;
    const int gate = gg & 3, H = gg >> 2;
    const int lane = threadIdx.x;       // 0..63
    const int row  = gate * 64 + H * 32 + (lane & 31);
    const float sc = (gate == 2) ? 2.0f * L2E : L2E;
    short8v v;
#pragma unroll
    for (int u = 0; u < 8; u++) {
        const int k = cc * 16 + (lane >> 5) * 8 + u;
        const float f = (k < 32) ? wih[row * 32 + k] : whh[row * 64 + (k - 32)];
        v[u] = f2bf(f * sc);
    }
    *(short8v*)&pB[((size_t)fi * 64 + lane) * 8] = v;
    if (cc == 0 && lane < 32)
        pbias[H * 128 + gate * 32 + lane] = (bih[row] + bhh[row]) * sc;
}

__global__ __launch_bounds__(256, 2) void k_encoder(
    const float* __restrict__ ctx_raw,  // (T, B, 2)
    const float* __restrict__ nbr_raw,  // (T, N, 2)
    const float* __restrict__ ipw, const float* __restrict__ ipb,
    const short* __restrict__ pB, const float* __restrict__ pbias,
    float* __restrict__ hfin)           // [S_TOT][64]
{
    __shared__ short hx2[2 * 64 * HXS];
    const int tid  = threadIdx.x;
    const int lane = tid & 63;
    const int w    = __builtin_amdgcn_readfirstlane(tid >> 6);  // 0..3
    const int H    = w >> 1;
    const int M0   = (w & 1) * 32;
    const int seq_base = blockIdx.x * 64;
    const bool is_hist = (seq_base < NB);

    short8v Bf[4][6];
#pragma unroll
    for (int gate = 0; gate < 4; gate++)
#pragma unroll
        for (int cc = 0; cc < 6; cc++)
            Bf[gate][cc] = *(const short8v*)
                &pB[(((size_t)(H * 4 + gate) * 6 + cc) * 64 + lane) * 8];

    float b4[4];
#pragma unroll
    for (int gate = 0; gate < 4; gate++)
        b4[gate] = pbias[H * 128 + gate * 32 + (lane & 31)];

    {
        short8v z;
#pragma unroll
        for (int u = 0; u < 8; u++) z[u] = 0;
        for (int i = tid; i < 64 * 8; i += 256)
            *(short8v*)&hx2[(i >> 3) * HXS + 32 + (i & 7) * 8] = z;
    }

    const int sx = seq_base + (tid & 63);
    float2 f2;
    {
        const float* rp = is_hist ? &ctx_raw[(size_t)sx * 2]
                                  : &nbr_raw[(size_t)(sx - NB) * 2];
        f2 = *(const float2*)rp;
        const int k0 = (tid >> 6) * 8;
        short8v xv;
#pragma unroll
        for (int u = 0; u < 8; u++) {
            const int xj = k0 + u;
            xv[u] = f2bf(lrelu(ipb[xj] + ipw[xj * 2] * f2.x + ipw[xj * 2 + 1] * f2.y));
        }
        *(short8v*)&hx2[(tid & 63) * HXS + k0] = xv;
    }
    __syncthreads();

    float cst[16];
#pragma unroll
    for (int r = 0; r < 16; r++) cst[r] = 0.0f;

    const int aoff = (M0 + (lane & 31)) * HXS + (lane >> 5) * 8;
    const int hcol = 32 + H * 32 + (lane & 31);

#pragma unroll 1
    for (int t = 0; t < TT; t++) {
        short* cur = hx2 + (t & 1) * (64 * HXS);
        short* nxt = hx2 + ((t + 1) & 1) * (64 * HXS);

        float2 f2n = f2;
        if (t < TT - 1) {
            const float* rp = is_hist
                ? &ctx_raw[((size_t)(t + 1) * NB + sx) * 2]
                : &nbr_raw[((size_t)(t + 1) * NNB + (sx - NB)) * 2];
            f2n = *(const float2*)rp;
        }

        short8v Af[6];
#pragma unroll
        for (int cc = 0; cc < 6; cc++)
            Af[cc] = *(const short8v*)&cur[aoff + cc * 16];

        f32x16 C[4];
#pragma unroll
        for (int gate = 0; gate < 4; gate++)
#pragma unroll
            for (int r = 0; r < 16; r++) C[gate][r] = b4[gate];

#pragma unroll
        for (int cc = 0; cc < 6; cc++)
#pragma unroll
            for (int gate = 0; gate < 4; gate++)
                C[gate] = __builtin_amdgcn_mfma_f32_32x32x16_bf16(
                    Af[cc], Bf[gate][cc], C[gate], 0, 0, 0);

        // pointwise, fused reciprocals: i*g and o*tanh(c) share one rcp each
        float hn[16];
#pragma unroll
        for (int r = 0; r < 16; r++) {
            const float ei = exp2f(-C[0][r]);
            const float ef = exp2f(-C[1][r]);
            const float eg = exp2f(C[2][r]);
            const float eo = exp2f(-C[3][r]);
            const float ivgv = (eg - 1.0f) * rcpf((1.0f + ei) * (eg + 1.0f));
            const float cn = cst[r] * rcpf(1.0f + ef) + ivgv;
            cst[r] = cn;
            const float ec = exp2f(cn * (2.0f * L2E));
            hn[r] = (ec - 1.0f) * rcpf((1.0f + eo) * (ec + 1.0f));
        }

        if (t < TT - 1) {
#pragma unroll
            for (int r = 0; r < 16; r++) {
                const int row = (r & 3) + 8 * (r >> 2) + 4 * (lane >> 5);
                nxt[(M0 + row) * HXS + hcol] = f2bf(hn[r]);
            }
            const int k0 = (tid >> 6) * 8;
            short8v xv;
#pragma unroll
            for (int u = 0; u < 8; u++) {
                const int xj = k0 + u;
                xv[u] = f2bf(lrelu(ipb[xj] + ipw[xj * 2] * f2n.x + ipw[xj * 2 + 1] * f2n.y));
            }
            *(short8v*)&nxt[(tid & 63) * HXS + k0] = xv;
            __syncthreads();   // single barrier per step
            f2 = f2n;
        } else {
#pragma unroll
            for (int r = 0; r < 16; r++) {
                const int row = (r & 3) + 8 * (r >> 2) + 4 * (lane >> 5);
                hfin[(size_t)(seq_base + M0 + row) * 64 + H * 32 + (lane & 31)] = hn[r];
            }
        }
    }
}

// ===========================================================================
// ATTENTION
// ===========================================================================
__global__ __launch_bounds__(256) void k_attn(
    const float* __restrict__ h_enc,    // [S_TOT][64]
    const float* __restrict__ dynw, const float* __restrict__ dynb,
    const float* __restrict__ l1w,  const float* __restrict__ l1b,
    float* __restrict__ ctx)            // [B][96]
{
    const int b   = blockIdx.x;
    const int tid = threadIdx.x;
    __shared__ float sh_he[32];
    __shared__ float sh_soc[20][65];
    __shared__ float sh_e[20];

    if (tid < 32) {
        float a = dynb[tid];
        const float* w  = &dynw[tid * 64];
        const float* hb = &h_enc[(size_t)b * 64];
#pragma unroll 8
        for (int k = 0; k < 64; k++) a += w[k] * hb[k];
        a = lrelu(a);
        sh_he[tid] = a;
        ctx[b * 96 + tid] = a;
    }
    for (int idx = tid; idx < 20 * 64; idx += 256) {
        const int g = idx >> 6, k = idx & 63;
        sh_soc[g][k] = h_enc[(size_t)(NB + b * 20 + g) * 64 + k];
    }
    __syncthreads();

    if (tid < 20) {
        float e = l1b[0];
#pragma unroll
        for (int m = 0; m < 32; m++) e += l1w[m] * tanhx(sh_he[m]);
#pragma unroll 8
        for (int k = 0; k < 64; k++) e += l1w[32 + k] * tanhx(sh_soc[tid][k]);
        sh_e[tid] = e;
    }
    __syncthreads();

    if (tid < 64) {
        float mx = -1e30f;
#pragma unroll
        for (int g = 0; g < 20; g++) mx = fmaxf(mx, sh_e[g]);
        float wgt[20];
        float sm = 0.0f;
#pragma unroll
        for (int g = 0; g < 20; g++) { wgt[g] = exp2f((sh_e[g] - mx) * L2E); sm += wgt[g]; }
        const float inv = 1.0f / sm;
        float a = 0.0f;
#pragma unroll
        for (int g = 0; g < 20; g++) a += wgt[g] * sh_soc[g][tid];
        ctx[b * 96 + 32 + tid] = a * inv;
    }
}

// ===========================================================================
// DECODER
// ===========================================================================
__global__ __launch_bounds__(256) void k_pack_decB(
    const float* __restrict__ whh,   // (1024,256)
    const float* __restrict__ opw,   // (5,256)
    short* __restrict__ pBd, short* __restrict__ opwB)
{
    const int bid  = blockIdx.x;     // 0..127 = hg*16+cc ; 128..143 = opw cc
    const int tid  = threadIdx.x;
    const int lane = tid & 63;
    if (bid < 128) {
        const int gate = tid >> 6;
        const int hg = bid >> 4, cc = bid & 15;
        const int row  = gate * 256 + hg * 32 + (lane & 31);
        const int kb   = cc * 16 + (lane >> 5) * 8;
        const float sc = (gate == 2) ? 2.0f * L2E : L2E;
        short8v v;
#pragma unroll
        for (int u = 0; u < 8; u++) v[u] = f2bf(whh[row * 256 + kb + u] * sc);
        *(short8v*)&pBd[((size_t)(bid * 4 + gate) * 64 + lane) * 8] = v;
    } else if (tid < 64) {
        const int cc = bid - 128;
        const int n  = lane & 31, kb = cc * 16 + (lane >> 5) * 8;
        short8v v;
#pragma unroll
        for (int u = 0; u < 8; u++)
            v[u] = (n < 5) ? f2bf(opw[n * 256 + kb + u]) : (short)0;
        *(short8v*)&opwB[(cc * 64 + lane) * 8] = v;
    }
}

// Input-gate GEMM -> pgx[agent][j][gate] float4-packed, exp2 scale folded.
__global__ __launch_bounds__(256) void k_gx(
    const float* __restrict__ ctx,
    const float* __restrict__ wih,
    const float* __restrict__ bih, const float* __restrict__ bhh,
    float* __restrict__ pgx)            // [NB][256][4]
{
    const int lane = threadIdx.x & 63;
    const int s    = blockIdx.x * 64 + lane;
    const int jq   = __builtin_amdgcn_readfirstlane(blockIdx.y * 4 + (threadIdx.x >> 6));
    const int j0   = jq * 4;
    float acc[4];
#pragma unroll
    for (int d = 0; d < 4; d++) acc[d] = bih[j0 + d] + bhh[j0 + d];
    const float* c = &ctx[(size_t)s * 96];
    for (int k0 = 0; k0 < 96; k0 += 8) {
        float cb[8];
#pragma unroll
        for (int u = 0; u < 8; u++) cb[u] = c[k0 + u];
#pragma unroll
        for (int d = 0; d < 4; d++) {
            const float* w = &wih[(j0 + d) * 96 + k0];
#pragma unroll
            for (int u = 0; u < 8; u++) acc[d] += w[u] * cb[u];
        }
    }
#pragma unroll
    for (int d = 0; d < 4; d++) {
        const int row = j0 + d;
        const int g = row >> 8, j = row & 255;
        const float sc = (g == 2) ? 2.0f * L2E : L2E;
        pgx[(((size_t)s << 8) + j) * 4 + g] = acc[d] * sc;
    }
}

// stage cc-group ccv (4 frags x 1KB) into this wave's LDS buffer bufv
#define STAGE(ccv, bufv) do {                                              \
    const short* gs = wb + (size_t)(ccv) * 2048 + lane * 8;                \
    short* ls = &wstg[w][bufv][0];                                         \
    gl2lds(gs + 0,    ls + 0);                                             \
    gl2lds(gs + 512,  ls + 512);                                           \
    gl2lds(gs + 1024, ls + 1024);                                          \
    gl2lds(gs + 1536, ls + 1536);                                          \
} while (0)

// one cc iteration: wait stage(ccv) landed, ds_read frags+Af(+Of), free the
// buffer (lgkm drain), restage ccv+2, MFMA.
#define DOCC(ccv, bufv, VMC, DOSTAGE) do {                                 \
    asm volatile("s_waitcnt vmcnt(" VMC ")" ::: "memory");                 \
    __builtin_amdgcn_sched_barrier(0);                                     \
    const short8v W0 = *(const short8v*)&wstg[w][bufv][0 * 512 + lane * 8];\
    const short8v W1 = *(const short8v*)&wstg[w][bufv][1 * 512 + lane * 8];\
    const short8v W2 = *(const short8v*)&wstg[w][bufv][2 * 512 + lane * 8];\
    const short8v W3 = *(const short8v*)&wstg[w][bufv][3 * 512 + lane * 8];\
    const short8v Af = *(const short8v*)                                   \
        (cur + n * 512 + (((ccv) * 32 + hl * 16) ^ ((n & 7) << 4)));       \
    short8v Of;                                                            \
    if (headw) Of = *(const short8v*)&ldsO[(ccv) * 512 + lane * 8];        \
    asm volatile("s_waitcnt lgkmcnt(0)" ::: "memory");                     \
    __builtin_amdgcn_sched_barrier(0);                                     \
    if (DOSTAGE) STAGE((ccv) + 2, bufv);                                   \
    C[0] = __builtin_amdgcn_mfma_f32_32x32x16_bf16(Af, W0, C[0], 0, 0, 0); \
    C[1] = __builtin_amdgcn_mfma_f32_32x32x16_bf16(Af, W1, C[1], 0, 0, 0); \
    C[2] = __builtin_amdgcn_mfma_f32_32x32x16_bf16(Af, W2, C[2], 0, 0, 0); \
    C[3] = __builtin_amdgcn_mfma_f32_32x32x16_bf16(Af, W3, C[3], 0, 0, 0); \
    if (headw)                                                             \
        Ch = __builtin_amdgcn_mfma_f32_32x32x16_bf16(Af, Of, Ch, 0, 0, 0); \
} while (0)

// Persistent decoder. 128 blocks x 512 threads; block = 32 agents x all 256
// hidden, wave w = hidden-group w. h double-buffered in LDS (bijective
// column-XOR swizzle). Weights async-staged per wave (private LDS double
// buffer, counted vmcnt(4)). c in registers. Head fused on wave 0.
__global__ __launch_bounds__(512, 1) void k_dec_persist(
    const float* __restrict__ pgx,    // [NB][256][4]
    const short* __restrict__ pBd,    // [8][16][4][64][8] bf16
    const short* __restrict__ opwB,   // [16][64][8] bf16
    const float* __restrict__ opb,
    float* __restrict__ out)
{
    __shared__ short hbuf[2][32 * 256];   // 32 KB
    __shared__ short wstg[8][2][2048];    // 64 KB  [wave][buf][frag*512+lane*8]
    __shared__ short ldsO[16 * 512];      // 16 KB  head weights
    const int tid  = threadIdx.x;
    const int lane = tid & 63;
    const int w    = __builtin_amdgcn_readfirstlane(tid >> 6);  // 0..7 = hg
    const int Ab   = blockIdx.x * 32;
    const int n    = lane & 31;
    const int hl   = lane >> 5;           // 0/1
    const bool headw = (w == 0);

    const short* wb = pBd + (size_t)w * 32768;   // wave's weight slice

    // stage head weights once (wave 0's private use; its own vmcnt covers it)
    if (headw) {
#pragma unroll
        for (int i = 0; i < 16; i++)
            gl2lds(opwB + i * 512 + lane * 8, &ldsO[i * 512]);
    }

    float cst[16];
#pragma unroll
    for (int r = 0; r < 16; r++) cst[r] = 0.0f;

#pragma unroll 1
    for (int t = 0; t < NFUT; t++) {
        const char* cur = (const char*)hbuf[t & 1];
        char* nxt       = (char*)hbuf[(t + 1) & 1];

        f32x16 C[4], Ch;
#pragma unroll
        for (int g = 0; g < 4; g++)
#pragma unroll
            for (int r = 0; r < 16; r++) C[g][r] = 0.0f;
#pragma unroll
        for (int r = 0; r < 16; r++) Ch[r] = 0.0f;

        if (t > 0) {
            STAGE(0, 0);
            STAGE(1, 1);
#pragma unroll 1
            for (int c2 = 0; c2 < 14; c2 += 2) {
                DOCC(c2,     0, "4", 1);
                DOCC(c2 + 1, 1, "4", 1);
            }
            DOCC(14, 0, "4", 0);
            DOCC(15, 1, "0", 0);
        }

        // pointwise (fused reciprocals): lane owns j = 32w+n, 16 agent rows
#pragma unroll
        for (int r = 0; r < 16; r++) {
            const int al = (r & 3) + 8 * (r >> 2) + 4 * hl;   // 0..31
            const float4 g4 = *(const float4*)
                &pgx[(((size_t)(Ab + al) << 8) + w * 32 + n) * 4];
            const float ei = exp2f(-(C[0][r] + g4.x));
            const float ef = exp2f(-(C[1][r] + g4.y));
            const float eg = exp2f(C[2][r] + g4.z);
            const float eo = exp2f(-(C[3][r] + g4.w));
            const float ivgv = (eg - 1.0f) * rcpf((1.0f + ei) * (eg + 1.0f));
            const float cn = cst[r] * rcpf(1.0f + ef) + ivgv;
            cst[r] = cn;
            const float ec = exp2f(cn * (2.0f * L2E));
            const float hv = (ec - 1.0f) * rcpf((1.0f + eo) * (ec + 1.0f));
            const int hbyte = al * 512 + (((w * 32 + n) * 2) ^ ((al & 7) << 4));
            *(short*)(nxt + hbyte) = f2bf(hv);
        }

        // output head for step t-1 (from h_t = cur)
        if (t > 0 && headw && n < 5) {
            const float obias = opb[n];
#pragma unroll
            for (int r = 0; r < 16; r++) {
                const int agent = Ab + (r & 3) + 8 * (r >> 2) + 4 * hl;
                float v = Ch[r] + obias;
                if (n == 2 || n == 3) v = exp2f(v * L2E);
                else if (n == 4) v = tanhx(v);
                out[(size_t)agent * (NFUT * 5) + (t - 1) * 5 + n] = v;
            }
        }

        __syncthreads();
    }

    // final head: out[23] from h_24 = hbuf[NFUT & 1] (= hbuf[0])
    if (headw) {
        const char* cur = (const char*)hbuf[NFUT & 1];
        f32x16 Ch;
#pragma unroll
        for (int r = 0; r < 16; r++) Ch[r] = 0.0f;
#pragma unroll 4
        for (int cc = 0; cc < 16; cc++) {
            const int abyte = n * 512 + ((cc * 32 + hl * 16) ^ ((n & 7) << 4));
            const short8v Af = *(const short8v*)(cur + abyte);
            const short8v Of = *(const short8v*)&ldsO[cc * 512 + lane * 8];
            Ch = __builtin_amdgcn_mfma_f32_32x32x16_bf16(Af, Of, Ch, 0, 0, 0);
        }
        if (n < 5) {
            const float obias = opb[n];
#pragma unroll
            for (int r = 0; r < 16; r++) {
                const int agent = Ab + (r & 3) + 8 * (r >> 2) + 4 * hl;
                float v = Ch[r] + obias;
                if (n == 2 || n == 3) v = exp2f(v * L2E);
                else if (n == 4) v = tanhx(v);
                out[(size_t)agent * (NFUT * 5) + (NFUT - 1) * 5 + n] = v;
            }
        }
    }
}

extern "C" void kernel_launch(void* const* d_in, const int* in_sizes, int n_in,
                              void* d_out, int out_size, void* d_ws, size_t ws_size,
                              hipStream_t stream)
{
    // 0:x 1:beta 2:context 3:nbrs 4:mask 5:ip_w 6:ip_b 7:enc_wih 8:enc_whh
    // 9:enc_bih 10:enc_bhh 11:dyn_w 12:dyn_b 13:lin1_w 14:lin1_b 15:dec_wih
    // 16:dec_whh 17:dec_bih 18:dec_bhh 19:op_w 20:op_b
    const float* ctx_raw = (const float*)d_in[2];
    const float* nbr_raw = (const float*)d_in[3];
    const float* ipw     = (const float*)d_in[5];
    const float* ipb     = (const float*)d_in[6];
    const float* enc_wih = (const float*)d_in[7];
    const float* enc_whh = (const float*)d_in[8];
    const float* enc_bih = (const float*)d_in[9];
    const float* enc_bhh = (const float*)d_in[10];
    const float* dynw    = (const float*)d_in[11];
    const float* dynb    = (const float*)d_in[12];
    const float* l1w     = (const float*)d_in[13];
    const float* l1b     = (const float*)d_in[14];
    const float* dec_wih = (const float*)d_in[15];
    const float* dec_whh = (const float*)d_in[16];
    const float* dec_bih = (const float*)d_in[17];
    const float* dec_bhh = (const float*)d_in[18];
    const float* opw     = (const float*)d_in[19];
    const float* opb     = (const float*)d_in[20];
    float* out = (float*)d_out;

    // workspace carve-up (~40 MB)
    char* pc = (char*)d_ws;
    float* hfin  = (float*)pc; pc += (size_t)S_TOT * 64 * 4;
    float* ctxb  = (float*)pc; pc += (size_t)NB * 96 * 4;
    float* pgx   = (float*)pc; pc += (size_t)NB * 1024 * 4;
    float* pbias = (float*)pc; pc += 256 * 4;
    short* pB    = (short*)pc; pc += (size_t)48 * 64 * 8 * 2;
    short* pBd   = (short*)pc; pc += (size_t)8 * 16 * 4 * 64 * 8 * 2;
    short* opwB  = (short*)pc; pc += (size_t)16 * 64 * 8 * 2;

    k_pack_encB<<<dim3(48), 64, 0, stream>>>(enc_wih, enc_whh, enc_bih, enc_bhh,
                                             pB, pbias);
    k_pack_decB<<<dim3(144), 256, 0, stream>>>(dec_whh, opw, pBd, opwB);

    k_encoder<<<dim3(S_TOT / 64), 256, 0, stream>>>(
        ctx_raw, nbr_raw, ipw, ipb, pB, pbias, hfin);

    k_attn<<<dim3(NB), 256, 0, stream>>>(hfin, dynw, dynb, l1w, l1b, ctxb);

    k_gx<<<dim3(NB / 64, 64), 256, 0, stream>>>(ctxb, dec_wih, dec_bih, dec_bhh, pgx);

    k_dec_persist<<<dim3(NB / 32), 512, 0, stream>>>(pgx, pBd, opwB, opb, out);
}